// Round 3
// baseline (344.566 us; speedup 1.0000x reference)
//
#include <hip/hip_runtime.h>
#include <math.h>

// ---------------------------------------------------------------------------
// GATPolicy: 3x GATConv (with self loops) + mean-pool + MLP head.
// CSR-by-dst built with ZERO global atomics (device-scope atomicAdd on gfx950
// bypasses the non-coherent XCD L2s -> ~48MB line write-through + 14G/s cap;
// measured 56us in r1). Two-level bucket scheme, LDS atomics only:
//   P1  per-block LDS hist over bucket=dst>>8 [fused: transform0 + W pack]
//   scanA  exclusive scan of histT[bucket][block]
//   P3  re-read edges, LDS rank within (block,bucket), write (src, dst&255)
//       into bucket-partitioned esrc/dsub8 (contiguous per-(block,bucket))
//   P4  ONE kernel per bucket: LDS count of dst&255 -> block scan -> row_ptr
//       (= offs[b*G1] + local excl) -> col scatter via LDS cursors. (was 4
//       dispatches: subcount/scanB/scanB_fin/col_scatter; bucket edges stay
//       L2-hot between the two passes.)
// Ranks are arbitrary-but-distinct, valid for order-independent aggregation.
// Requires n <= 65536 (bucket fits 8 bits x 256 entries); N=50000 here.
// Mean-pool is FUSED INTO MLP: batch is sorted, so block b binary-searches
// its node range [gs,ge) and sums rows directly — the old pool_kernel's
// ~205k contended global f32 atomics (same 16KB of lines) are gone.
// h stored FP8 e4m3 head-interleaved; agg inner loop 8-wide broadcast-consume.
// Inter-layer features bf16; K=128 transforms via mfma_f32_16x16x32_bf16.
// (r13 lesson: never chain blocks across XCDs.)
// ---------------------------------------------------------------------------

#define LRELU(x) ((x) > 0.f ? (x) : 0.2f * (x))

typedef short bf16x8 __attribute__((ext_vector_type(8)));
typedef float f32x4 __attribute__((ext_vector_type(4)));
typedef float f32x2 __attribute__((ext_vector_type(2)));

__device__ __forceinline__ float readlane_f(float v, int lane) {
    return __int_as_float(__builtin_amdgcn_readlane(__float_as_int(v), lane));
}
__device__ __forceinline__ unsigned readlane_u(unsigned v, int lane) {
    return (unsigned)__builtin_amdgcn_readlane((int)v, lane);
}
__device__ __forceinline__ unsigned short f2bf(float f) {
    unsigned int u = __float_as_uint(f);
    u = (u + 0x7fffu + ((u >> 16) & 1u)) >> 16;  // RNE
    return (unsigned short)u;
}
__device__ __forceinline__ float bf2f(unsigned short u) {
    return __uint_as_float((unsigned int)u << 16);
}
__device__ __forceinline__ unsigned char f2fp8(float f) {
    return (unsigned char)(__builtin_amdgcn_cvt_pk_fp8_f32(f, f, 0, false) & 0xff);
}
__device__ __forceinline__ f32x2 fp8pair(unsigned int u) {
    return __builtin_amdgcn_cvt_pk_f32_fp8(u, false);  // bytes 0,1
}

// -- P1: bucket hist (LDS only) || layer-0 transform (K=8) || W pack --------
// block ranges: [0,G1) hist, [G1, G1+t0b) transform0, rest W pack.

__global__ __launch_bounds__(256) void hist_t0_kernel(
    const int* __restrict__ dst, int* __restrict__ histT,
    int e, int G1, int NB, int n, int hist_blocks, int t0_blocks,
    const float* __restrict__ x, const float* __restrict__ W,
    const float* __restrict__ a_src, const float* __restrict__ a_dst,
    unsigned char* __restrict__ h, float* __restrict__ as_o,
    float* __restrict__ ad_o,
    const float* __restrict__ W1, const float* __restrict__ W2,
    unsigned short* __restrict__ Wf1, unsigned short* __restrict__ Wf2) {
    __shared__ unsigned int hist[256];
    __shared__ float xs[2][8][8];
    if ((int)blockIdx.x < hist_blocks) {
        hist[threadIdx.x] = 0;
        __syncthreads();
        int base = blockIdx.x * 2048 + threadIdx.x * 8;
        int d[8];
        if (base + 8 <= e) {
            int4 x0 = *(const int4*)(dst + base);
            int4 x1 = *(const int4*)(dst + base + 4);
            d[0] = x0.x; d[1] = x0.y; d[2] = x0.z; d[3] = x0.w;
            d[4] = x1.x; d[5] = x1.y; d[6] = x1.z; d[7] = x1.w;
        } else {
#pragma unroll
            for (int j = 0; j < 8; j++) {
                int ij = base + j;
                d[j] = (ij < e) ? dst[ij] : -1;
            }
        }
#pragma unroll
        for (int j = 0; j < 8; j++) {
            if (d[j] >= 0) atomicAdd(&hist[d[j] >> 8], 1u);
        }
        __syncthreads();
        int b = threadIdx.x;
        if (b < NB) histT[b * G1 + blockIdx.x] = (int)hist[b];
        return;
    }
    if ((int)blockIdx.x < hist_blocks + t0_blocks) {
        // ---- transform0 path: h(fp8)=x@W0, as/ad. 16 nodes/block ----
        const int bid2 = blockIdx.x - hist_blocks;
        const int tid = threadIdx.x & 127;
        const int half = threadIdx.x >> 7;
        const int node0 = bid2 * 16 + half * 8;

        for (int idx = tid; idx < 64; idx += 128) {
            int ni = idx >> 3, k = idx & 7;
            int ng = node0 + ni;
            xs[half][ni][k] = (ng < n) ? x[(size_t)ng * 8 + k] : 0.f;
        }
        __syncthreads();

        float acc[8];
#pragma unroll
        for (int i = 0; i < 8; i++) acc[i] = 0.f;
#pragma unroll
        for (int k = 0; k < 8; k++) {
            float wk = W[k * 128 + tid];
#pragma unroll
            for (int i = 0; i < 8; i++) acc[i] += xs[half][i][k] * wk;
        }

        const int lane = tid & 63;
        const int head = tid >> 6;
        const int pos = 2 * lane + head;  // 2-head interleaved fp8 byte pos
        const float av = a_src[tid];
        const float dv = a_dst[tid];
#pragma unroll
        for (int i = 0; i < 8; i++) {
            int ng = node0 + i;
            if (ng >= n) break;
            h[(size_t)ng * 128 + pos] = f2fp8(acc[i]);
            float ps = acc[i] * av, pd = acc[i] * dv;
            for (int off = 32; off; off >>= 1) {
                ps += __shfl_xor(ps, off, 64);
                pd += __shfl_xor(pd, off, 64);
            }
            if (lane == 0) {
                as_o[ng * 2 + head] = ps;
                ad_o[ng * 2 + head] = pd;
            }
        }
        return;
    }
    // ---- W pack path ----
    const int n1 = 8 * 4 * 64;   // W1 fragment rows (OUT=128)
    const int n2 = 4 * 4 * 64;   // W2 fragment rows (OUT=64)
    int gid = (blockIdx.x - hist_blocks - t0_blocks) * 256 + threadIdx.x;
    if (gid < n1) {
        int idx = gid;
        int lane = idx & 63, ts = idx >> 6;
        int s = ts & 3, t = ts >> 2;
        int quad = lane >> 4, cn = lane & 15;
#pragma unroll
        for (int j = 0; j < 8; j++)
            Wf1[idx * 8 + j] = f2bf(W1[(s * 32 + quad * 8 + j) * 128 + t * 16 + cn]);
    } else if (gid < n1 + n2) {
        int idx = gid - n1;
        int lane = idx & 63, ts = idx >> 6;
        int s = ts & 3, t = ts >> 2;
        int quad = lane >> 4, cn = lane & 15;
#pragma unroll
        for (int j = 0; j < 8; j++)
            Wf2[idx * 8 + j] = f2bf(W2[(s * 32 + quad * 8 + j) * 64 + t * 16 + cn]);
    }
}

// ---------------- generalized scan: 512 elements per block -----------------

__global__ __launch_bounds__(256) void scan2_block_kernel(
    const int* __restrict__ in, int* __restrict__ out,
    int* __restrict__ blockSums, int len) {
    __shared__ int lds[256];
    int t = threadIdx.x;
    int i0 = blockIdx.x * 512 + 2 * t;
    int v0 = (i0 < len) ? in[i0] : 0;
    int v1 = (i0 + 1 < len) ? in[i0 + 1] : 0;
    int s = v0 + v1;
    lds[t] = s;
    __syncthreads();
    for (int off = 1; off < 256; off <<= 1) {
        int u = (t >= off) ? lds[t - off] : 0;
        __syncthreads();
        lds[t] += u;
        __syncthreads();
    }
    int base = lds[t] - s;  // block-local exclusive for element i0
    if (i0 < len) out[i0] = base;
    if (i0 + 1 < len) out[i0 + 1] = base + v0;
    if (t == 255) blockSums[blockIdx.x] = lds[255];
}

// Every block redundantly scans blockSums (nb <= 256) and applies its base.
// Also writes out[len] = total.
__global__ __launch_bounds__(256) void scan2_finalize_kernel(
    int* __restrict__ out, const int* __restrict__ blockSums, int len, int nb) {
    __shared__ int lds[256];
    int t = threadIdx.x;
    int v = (t < nb) ? blockSums[t] : 0;
    lds[t] = v;
    __syncthreads();
    for (int off = 1; off < 256; off <<= 1) {
        int u = (t >= off) ? lds[t - off] : 0;
        __syncthreads();
        lds[t] += u;
        __syncthreads();
    }
    const int bid = blockIdx.x;
    const int base = (bid > 0) ? lds[bid - 1] : 0;
    const int total = lds[nb - 1];
    int i0 = bid * 512 + 2 * t;
#pragma unroll
    for (int q = 0; q < 2; q++) {
        int i = i0 + q;
        if (i < len) out[i] += base;
        else if (i == len) out[len] = total;
    }
}

// ---------------- P3: bucket partition (LDS ranks, no global atomics) ------

__global__ __launch_bounds__(256) void bucket_scatter_kernel(
    const int* __restrict__ src, const int* __restrict__ dst,
    const int* __restrict__ offs, int* __restrict__ esrc,
    unsigned char* __restrict__ dsub8, int e, int G1) {
    __shared__ unsigned int hist[256];
    hist[threadIdx.x] = 0;
    __syncthreads();
    int base = blockIdx.x * 2048 + threadIdx.x * 8;
    int d[8], s[8];
    if (base + 8 <= e) {
        int4 d0 = *(const int4*)(dst + base);
        int4 d1 = *(const int4*)(dst + base + 4);
        int4 s0 = *(const int4*)(src + base);
        int4 s1 = *(const int4*)(src + base + 4);
        d[0] = d0.x; d[1] = d0.y; d[2] = d0.z; d[3] = d0.w;
        d[4] = d1.x; d[5] = d1.y; d[6] = d1.z; d[7] = d1.w;
        s[0] = s0.x; s[1] = s0.y; s[2] = s0.z; s[3] = s0.w;
        s[4] = s1.x; s[5] = s1.y; s[6] = s1.z; s[7] = s1.w;
    } else {
#pragma unroll
        for (int j = 0; j < 8; j++) {
            int ij = base + j;
            bool v = ij < e;
            d[j] = v ? dst[ij] : -1;
            s[j] = v ? src[ij] : 0;
        }
    }
    unsigned lr[8];
#pragma unroll
    for (int j = 0; j < 8; j++) {
        lr[j] = (d[j] >= 0) ? atomicAdd(&hist[d[j] >> 8], 1u) : 0u;
    }
#pragma unroll
    for (int j = 0; j < 8; j++) {
        if (d[j] >= 0) {
            int pos = offs[(d[j] >> 8) * G1 + blockIdx.x] + (int)lr[j];
            esrc[pos] = s[j];
            dsub8[pos] = (unsigned char)(d[j] & 255);
        }
    }
}

// -------- P4: per-bucket CSR finalize: count -> scan -> row_ptr -> col -----
// row_ptr[b*256+t] = offs[b*G1] (edges in prior buckets) + local exclusive.
// Second pass scatters col via LDS cursors. One dispatch replaces four.

__global__ __launch_bounds__(256) void bucket_csr_kernel(
    const int* __restrict__ offs, const unsigned char* __restrict__ dsub8,
    const int* __restrict__ esrc, int* __restrict__ row_ptr,
    int* __restrict__ col, int G1, int n) {
    __shared__ unsigned int cnt[256];
    __shared__ int rp[256];
    int t = threadIdx.x;
    int b = blockIdx.x;
    cnt[t] = 0;
    __syncthreads();
    int bs = offs[b * G1];
    int be = offs[(b + 1) * G1];
    for (int i = bs + t; i < be; i += 256) {
        atomicAdd(&cnt[dsub8[i]], 1u);
    }
    __syncthreads();
    int v = (int)cnt[t];
    rp[t] = v;
    __syncthreads();
    for (int off = 1; off < 256; off <<= 1) {
        int u = (t >= off) ? rp[t - off] : 0;
        __syncthreads();
        rp[t] += u;
        __syncthreads();
    }
    int excl = rp[t] - v;
    int node = b * 256 + t;
    if (node <= n) row_ptr[node] = bs + excl;  // node==n lands here too (E)
    __syncthreads();
    cnt[t] = (unsigned)excl;  // running cursors
    __syncthreads();
    for (int i = bs + t; i < be; i += 256) {
        int sub = dsub8[i];
        unsigned r = atomicAdd(&cnt[sub], 1u);
        col[bs + (int)r] = esrc[i];
    }
}

// fp8 h byte position for channel c: 2-head interleaved pairs, 1-head flat
template <int OUT, int HEADS>
__device__ __forceinline__ int hpos8(int c) {
    return (HEADS == 2) ? (2 * (c & 63) + (c >> 6)) : c;
}

// ---------------- MFMA transform (K=128): h(fp8)=xb(bf16)@W, as/ad ---------

template <int OUT, int HEADS>
__global__ __launch_bounds__(256) void transform_mfma_kernel(
    const unsigned short* __restrict__ xb, const unsigned short* __restrict__ Wf,
    const float* __restrict__ a_src, const float* __restrict__ a_dst,
    unsigned char* __restrict__ h, float* __restrict__ as_o, float* __restrict__ ad_o,
    int n) {
    constexpr int T = OUT / 16, S = 4;  // K = 128
    const int w = threadIdx.x >> 6, lane = threadIdx.x & 63;
    const int node0 = (blockIdx.x * 4 + w) * 16;
    if (node0 >= n) return;
    const int quad = lane >> 4, col = lane & 15;

    const int arow = node0 + col;
    const bool aok = arow < n;
    bf16x8 a[S];
    const unsigned short* xrow = xb + (size_t)arow * 128 + quad * 8;
#pragma unroll
    for (int s = 0; s < S; s++) {
        bf16x8 z = {0, 0, 0, 0, 0, 0, 0, 0};
        a[s] = aok ? *(const bf16x8*)(xrow + s * 32) : z;
    }

    f32x4 acc[T];
#pragma unroll
    for (int t = 0; t < T; t++) acc[t] = (f32x4){0.f, 0.f, 0.f, 0.f};

#pragma unroll
    for (int s = 0; s < S; s++) {
#pragma unroll
        for (int t = 0; t < T; t++) {
            bf16x8 b = *(const bf16x8*)(Wf + ((size_t)(t * S + s) * 64 + lane) * 8);
            acc[t] = __builtin_amdgcn_mfma_f32_16x16x32_bf16(a[s], b, acc[t], 0, 0, 0);
        }
    }

#pragma unroll
    for (int t = 0; t < T; t++) {
        int pos = hpos8<OUT, HEADS>(t * 16 + col);
#pragma unroll
        for (int r = 0; r < 4; r++) {
            int m = node0 + quad * 4 + r;
            if (m < n) h[(size_t)m * OUT + pos] = f2fp8(acc[t][r]);
        }
    }

#pragma unroll
    for (int r = 0; r < 4; r++) {
        float s0 = 0.f, s1 = 0.f, d0 = 0.f, d1 = 0.f;
#pragma unroll
        for (int t = 0; t < T; t++) {
            float av = a_src[t * 16 + col];
            float dv = a_dst[t * 16 + col];
            float v = acc[t][r];
            if (HEADS == 2 && t >= T / 2) { s1 += v * av; d1 += v * dv; }
            else                          { s0 += v * av; d0 += v * dv; }
        }
        for (int off = 8; off; off >>= 1) {
            s0 += __shfl_xor(s0, off, 64);
            d0 += __shfl_xor(d0, off, 64);
            if (HEADS == 2) {
                s1 += __shfl_xor(s1, off, 64);
                d1 += __shfl_xor(d1, off, 64);
            }
        }
        int m = node0 + quad * 4 + r;
        if (m < n) {
            if (HEADS == 2) {
                if (col == 0)      { as_o[m * 2] = s0;     ad_o[m * 2] = d0; }
                else if (col == 1) { as_o[m * 2 + 1] = s1; ad_o[m * 2 + 1] = d1; }
            } else {
                if (col == 0) { as_o[m] = s0; ad_o[m] = d0; }
            }
        }
    }
}

// ---------------- GAT aggregation, 2 heads (fp8 h): one wave per node ------
// 8-wide serial consume: all 8 gather loads issue before the w broadcasts.

template <int ACT>  // 1 = elu
__global__ __launch_bounds__(256) void agg2_kernel(
    const int* __restrict__ row_ptr, const int* __restrict__ col,
    const unsigned char* __restrict__ h, const float2* __restrict__ as2,
    const float2* __restrict__ ad2, const float* __restrict__ bias,
    unsigned short* __restrict__ out, int n) {
    const int node = blockIdx.x * 4 + (threadIdx.x >> 6);
    const int lane = threadIdx.x & 63;
    if (node >= n) return;

    const int beg = row_ptr[node], end = row_ptr[node + 1];
    const float2 adv = ad2[node];
    const unsigned char* __restrict__ hb = h + 2 * lane;

    // self-loop
    const float2 avs = as2[node];
    float w0s = __expf(LRELU(avs.x + adv.x));
    float w1s = __expf(LRELU(avs.y + adv.y));
    unsigned int us = *(const unsigned short*)(hb + ((size_t)node << 7));
    f32x2 hvs = fp8pair(us);
    float accL = w0s * hvs.x, accH = w1s * hvs.y;
    float den0 = w0s, den1 = w1s;

    for (int base = beg; base < end; base += 64) {
        int cnt = end - base;
        if (cnt > 64) cnt = 64;
        int s = 0;
        float w0 = 0.f, w1 = 0.f;
        if (lane < cnt) {
            s = col[base + lane];
            float2 av = as2[s];
            w0 = __expf(LRELU(av.x + adv.x));
            w1 = __expf(LRELU(av.y + adv.y));
        }
        float t0 = w0, t1 = w1;
        for (int off = 32; off; off >>= 1) {
            t0 += __shfl_xor(t0, off, 64);
            t1 += __shfl_xor(t1, off, 64);
        }
        den0 += t0;
        den1 += t1;

        unsigned soff = (unsigned)s << 7;  // row byte offset (128 B)
        for (int j = 0; j < cnt; j += 8) {  // j <= 56; pads carry w=0
            unsigned o0 = readlane_u(soff, j);
            unsigned o1 = readlane_u(soff, j + 1);
            unsigned o2 = readlane_u(soff, j + 2);
            unsigned o3 = readlane_u(soff, j + 3);
            unsigned o4 = readlane_u(soff, j + 4);
            unsigned o5 = readlane_u(soff, j + 5);
            unsigned o6 = readlane_u(soff, j + 6);
            unsigned o7 = readlane_u(soff, j + 7);
            unsigned u0 = *(const unsigned short*)(hb + o0);
            unsigned u1 = *(const unsigned short*)(hb + o1);
            unsigned u2 = *(const unsigned short*)(hb + o2);
            unsigned u3 = *(const unsigned short*)(hb + o3);
            unsigned u4 = *(const unsigned short*)(hb + o4);
            unsigned u5 = *(const unsigned short*)(hb + o5);
            unsigned u6 = *(const unsigned short*)(hb + o6);
            unsigned u7 = *(const unsigned short*)(hb + o7);
            float a0 = readlane_f(w0, j),     a1 = readlane_f(w1, j);
            float b0 = readlane_f(w0, j + 1), b1 = readlane_f(w1, j + 1);
            float c0 = readlane_f(w0, j + 2), c1 = readlane_f(w1, j + 2);
            float d0 = readlane_f(w0, j + 3), d1 = readlane_f(w1, j + 3);
            float e0 = readlane_f(w0, j + 4), e1 = readlane_f(w1, j + 4);
            float f0 = readlane_f(w0, j + 5), f1 = readlane_f(w1, j + 5);
            float g0 = readlane_f(w0, j + 6), g1 = readlane_f(w1, j + 6);
            float i0 = readlane_f(w0, j + 7), i1 = readlane_f(w1, j + 7);
            f32x2 hA = fp8pair(u0);
            f32x2 hB = fp8pair(u1);
            f32x2 hC = fp8pair(u2);
            f32x2 hD = fp8pair(u3);
            f32x2 hE = fp8pair(u4);
            f32x2 hF = fp8pair(u5);
            f32x2 hG = fp8pair(u6);
            f32x2 hH = fp8pair(u7);
            accL += a0 * hA.x; accH += a1 * hA.y;
            accL += b0 * hB.x; accH += b1 * hB.y;
            accL += c0 * hC.x; accH += c1 * hC.y;
            accL += d0 * hD.x; accH += d1 * hD.y;
            accL += e0 * hE.x; accH += e1 * hE.y;
            accL += f0 * hF.x; accH += f1 * hF.y;
            accL += g0 * hG.x; accH += g1 * hG.y;
            accL += i0 * hH.x; accH += i1 * hH.y;
        }
    }

    float oL = accL / (den0 + 1e-16f) + bias[lane];
    float oH = accH / (den1 + 1e-16f) + bias[64 + lane];
    if (ACT) {
        oL = oL > 0.f ? oL : expm1f(oL);
        oH = oH > 0.f ? oH : expm1f(oH);
    }
    out[(size_t)node * 128 + lane] = f2bf(oL);
    out[(size_t)node * 128 + 64 + lane] = f2bf(oH);
}

// ---------------- GAT aggregation, 1 head (fp8 h, layer 2) -----------------
// Output bf16 (feeds pool only).

__global__ __launch_bounds__(256) void agg1_kernel(
    const int* __restrict__ row_ptr, const int* __restrict__ col,
    const unsigned char* __restrict__ h, const float* __restrict__ as1,
    const float* __restrict__ ad1, const float* __restrict__ bias,
    unsigned short* __restrict__ out, int n) {
    const int node = blockIdx.x * 4 + (threadIdx.x >> 6);
    const int lane = threadIdx.x & 63;
    if (node >= n) return;

    const int beg = row_ptr[node], end = row_ptr[node + 1];
    const float adv = ad1[node];
    const unsigned char* __restrict__ hb = h + lane;

    float ws = __expf(LRELU(as1[node] + adv));
    float acc = ws * fp8pair((unsigned)hb[(size_t)node << 6]).x;
    float den = ws;

    for (int base = beg; base < end; base += 64) {
        int cnt = end - base;
        if (cnt > 64) cnt = 64;
        int s = 0;
        float w = 0.f;
        if (lane < cnt) {
            s = col[base + lane];
            w = __expf(LRELU(as1[s] + adv));
        }
        float t = w;
        for (int off = 32; off; off >>= 1) t += __shfl_xor(t, off, 64);
        den += t;

        unsigned soff = (unsigned)s << 6;  // row byte offset (64 B)
        for (int j = 0; j < cnt; j += 8) {
            unsigned o0 = readlane_u(soff, j);
            unsigned o1 = readlane_u(soff, j + 1);
            unsigned o2 = readlane_u(soff, j + 2);
            unsigned o3 = readlane_u(soff, j + 3);
            unsigned o4 = readlane_u(soff, j + 4);
            unsigned o5 = readlane_u(soff, j + 5);
            unsigned o6 = readlane_u(soff, j + 6);
            unsigned o7 = readlane_u(soff, j + 7);
            unsigned u0 = hb[o0];
            unsigned u1 = hb[o1];
            unsigned u2 = hb[o2];
            unsigned u3 = hb[o3];
            unsigned u4 = hb[o4];
            unsigned u5 = hb[o5];
            unsigned u6 = hb[o6];
            unsigned u7 = hb[o7];
            float wA = readlane_f(w, j);
            float wB = readlane_f(w, j + 1);
            float wC = readlane_f(w, j + 2);
            float wD = readlane_f(w, j + 3);
            float wE = readlane_f(w, j + 4);
            float wF = readlane_f(w, j + 5);
            float wG = readlane_f(w, j + 6);
            float wH = readlane_f(w, j + 7);
            acc += wA * fp8pair(u0).x;
            acc += wB * fp8pair(u1).x;
            acc += wC * fp8pair(u2).x;
            acc += wD * fp8pair(u3).x;
            acc += wE * fp8pair(u4).x;
            acc += wF * fp8pair(u5).x;
            acc += wG * fp8pair(u6).x;
            acc += wH * fp8pair(u7).x;
        }
    }

    out[(size_t)node * 64 + lane] = f2bf(acc / (den + 1e-16f) + bias[lane]);
}

// ------- MLP head (pool fused): one block per graph, sorted-batch ranges ---

__global__ __launch_bounds__(256) void mlp_kernel(
    const unsigned short* __restrict__ xbuf, const int* __restrict__ batch,
    int n, const float* __restrict__ obs,
    const float* __restrict__ Ws1, const float* __restrict__ bs1,
    const float* __restrict__ ln_g, const float* __restrict__ ln_b,
    const float* __restrict__ Ws2, const float* __restrict__ bs2,
    const float* __restrict__ Wa, const float* __restrict__ ba,
    const float* __restrict__ Wc, const float* __restrict__ bc,
    float* __restrict__ out_logits, float* __restrict__ out_value) {
    int b = blockIdx.x;
    int t = threadIdx.x;
    __shared__ float comb[192];
    __shared__ float red[256];
    __shared__ float hs[256];

    // node range [gs, ge) for graph b (batch sorted)
    int lo = 0, hi = n;
    while (lo < hi) { int m = (lo + hi) >> 1; if (batch[m] < b) lo = m + 1; else hi = m; }
    const int gs = lo;
    hi = n;
    while (lo < hi) { int m = (lo + hi) >> 1; if (batch[m] < b + 1) lo = m + 1; else hi = m; }
    const int ge = lo;

    // pool: sum xbuf rows gs..ge over 4 row-groups
    {
        float acc = 0.f;
        int ch = t & 63, g = t >> 6;
        for (int i = gs + g; i < ge; i += 4)
            acc += bf2f(xbuf[(size_t)i * 64 + ch]);
        red[t] = acc;
        __syncthreads();
        if (t < 128) red[t] += red[t + 128];
        __syncthreads();
        if (t < 64) red[t] += red[t + 64];
        __syncthreads();
        float cdiv = fmaxf((float)(ge - gs), 1.f);
        if (t < 64) comb[t] = red[t] / cdiv;
        else if (t < 192) comb[t] = obs[b * 128 + (t - 64)];
    }
    __syncthreads();

    float accA = 0.f, accB = 0.f;
#pragma unroll 4
    for (int k = 0; k < 192; k += 2) {
        accA += comb[k] * Ws1[k * 256 + t];
        accB += comb[k + 1] * Ws1[(k + 1) * 256 + t];
    }
    float acc = bs1[t] + accA + accB;

    red[t] = acc;
    __syncthreads();
    for (int off = 128; off; off >>= 1) {
        if (t < off) red[t] += red[t + off];
        __syncthreads();
    }
    float mu = red[0] / 256.f;
    __syncthreads();
    float d = acc - mu;
    red[t] = d * d;
    __syncthreads();
    for (int off = 128; off; off >>= 1) {
        if (t < off) red[t] += red[t + off];
        __syncthreads();
    }
    float var = red[0] / 256.f;
    float hn = d * rsqrtf(var + 1e-5f) * ln_g[t] + ln_b[t];
    hn = hn > 0.f ? hn : 0.f;
    __syncthreads();
    hs[t] = hn;
    __syncthreads();

    float a2A = 0.f, a2B = 0.f;
#pragma unroll 4
    for (int k = 0; k < 256; k += 2) {
        a2A += hs[k] * Ws2[k * 256 + t];
        a2B += hs[k + 1] * Ws2[(k + 1) * 256 + t];
    }
    float acc2 = bs2[t] + a2A + a2B;
    acc2 = acc2 > 0.f ? acc2 : 0.f;
    __syncthreads();
    hs[t] = acc2;
    __syncthreads();

    // logits: 16 outputs x 16 k-chunks across all 256 threads + LDS tree
    {
        int o = t & 15, ck = t >> 4;
        float p = 0.f;
#pragma unroll
        for (int k = 0; k < 16; k++)
            p += hs[ck * 16 + k] * Wa[(ck * 16 + k) * 16 + o];
        red[t] = p;
    }
    __syncthreads();
    for (int off = 8; off >= 1; off >>= 1) {
        if ((t >> 4) < off) red[t] += red[t + off * 16];
        __syncthreads();
    }
    if (t < 16) out_logits[b * 16 + t] = red[t] + ba[t];
    __syncthreads();

    // value: full-width dot + tree
    red[t] = hs[t] * Wc[t];
    __syncthreads();
    for (int off = 128; off; off >>= 1) {
        if (t < off) red[t] += red[t + off];
        __syncthreads();
    }
    if (t == 0) out_value[b] = red[0] + bc[0];
}

// ---------------------------------------------------------------------------

extern "C" void kernel_launch(void* const* d_in, const int* in_sizes, int n_in,
                              void* d_out, int out_size, void* d_ws, size_t ws_size,
                              hipStream_t stream) {
    const float* obs    = (const float*)d_in[0];
    const float* nf     = (const float*)d_in[1];
    const int*   ei     = (const int*)d_in[2];
    const int*   batch  = (const int*)d_in[3];
    const float* W0     = (const float*)d_in[4];
    const float* a_src0 = (const float*)d_in[5];
    const float* a_dst0 = (const float*)d_in[6];
    const float* b0     = (const float*)d_in[7];
    const float* W1     = (const float*)d_in[8];
    const float* a_src1 = (const float*)d_in[9];
    const float* a_dst1 = (const float*)d_in[10];
    const float* b1     = (const float*)d_in[11];
    const float* W2     = (const float*)d_in[12];
    const float* a_src2 = (const float*)d_in[13];
    const float* a_dst2 = (const float*)d_in[14];
    const float* b2     = (const float*)d_in[15];
    const float* Ws1    = (const float*)d_in[16];
    const float* bs1    = (const float*)d_in[17];
    const float* ln_g   = (const float*)d_in[18];
    const float* ln_b   = (const float*)d_in[19];
    const float* Ws2    = (const float*)d_in[20];
    const float* bs2    = (const float*)d_in[21];
    const float* Wa     = (const float*)d_in[22];
    const float* ba     = (const float*)d_in[23];
    const float* Wc     = (const float*)d_in[24];
    const float* bc     = (const float*)d_in[25];

    const int N = in_sizes[3];
    const int E = in_sizes[2] / 2;
    const int B = in_sizes[0] / 128;
    const int* src = ei;
    const int* dstp = ei + E;

    // workspace carve (256B aligned)
    char* p = (char*)d_ws;
    auto alloc = [&](size_t bytes) -> void* {
        void* r = (void*)p;
        p += (bytes + 255) & ~(size_t)255;
        return r;
    };
    const int G1 = (E + 2047) / 2048;       // edge chunks (2048/block)
    const int NB = (N + 255) >> 8;          // dst buckets (n <= 65536)
    const int L  = NB * G1;                 // histT length
    int*   row_ptr   = (int*)alloc((size_t)(N + 1) * 4);
    int*   col       = (int*)alloc((size_t)E * 4);
    int*   esrc      = (int*)alloc((size_t)E * 4);           // bucketed src
    unsigned char* dsub8 = (unsigned char*)alloc((size_t)E); // bucketed dst&255
    int*   histT     = (int*)alloc((size_t)L * 4);
    int*   offs      = (int*)alloc((size_t)(L + 1) * 4);
    unsigned char* hbuf = (unsigned char*)alloc((size_t)N * 128);       // fp8 interleaved
    unsigned short* xb = (unsigned short*)alloc((size_t)N * 128 * 2);   // bf16 features
    unsigned short* xbuf = (unsigned short*)alloc((size_t)N * 64 * 2);  // final layer bf16
    float* as_       = (float*)alloc((size_t)N * 2 * 4);
    float* ad_       = (float*)alloc((size_t)N * 2 * 4);
    unsigned short* Wf1 = (unsigned short*)alloc((size_t)8 * 4 * 64 * 8 * 2);
    unsigned short* Wf2 = (unsigned short*)alloc((size_t)4 * 4 * 64 * 8 * 2);
    // scratch (blockSums) aliases xb region: scanA completes (stream-ordered)
    // before xb's first write (agg2, layer 0).
    int* blockSums = (int*)xb;   // up to 256 entries

    float* out_logits = (float*)d_out;
    float* out_value  = out_logits + (size_t)B * 16;

    // ---- P1: hist || transform0 || W pack (1 dispatch) ----
    int t0_blocks = (N + 15) / 16;
    int wp_blocks = (8 * 4 * 64 + 4 * 4 * 64 + 255) / 256;
    hist_t0_kernel<<<G1 + t0_blocks + wp_blocks, 256, 0, stream>>>(
        dstp, histT, E, G1, NB, N, G1, t0_blocks,
        nf, W0, a_src0, a_dst0, hbuf, as_, ad_,
        W1, W2, Wf1, Wf2);

    // ---- scanA over histT -> offs ----
    int nbA = (L + 511) / 512;
    scan2_block_kernel<<<nbA, 256, 0, stream>>>(histT, offs, blockSums, L);
    scan2_finalize_kernel<<<(L + 1 + 511) / 512, 256, 0, stream>>>(offs, blockSums, L, nbA);

    // ---- P3 bucket partition + P4 per-bucket CSR finalize ----
    bucket_scatter_kernel<<<G1, 256, 0, stream>>>(src, dstp, offs, esrc, dsub8, E, G1);
    bucket_csr_kernel<<<NB, 256, 0, stream>>>(offs, dsub8, esrc, row_ptr, col, G1, N);

    // ---- GAT layer 0 aggregation (transform fused into P1) ----
    agg2_kernel<1><<<(N + 3) / 4, 256, 0, stream>>>(
        row_ptr, col, hbuf, (const float2*)as_, (const float2*)ad_, b0, xb, N);

    // ---- GAT layer 1: in=128 -> concat, elu (MFMA transform) ----
    transform_mfma_kernel<128, 2><<<(N + 63) / 64, 256, 0, stream>>>(
        xb, Wf1, a_src1, a_dst1, hbuf, as_, ad_, N);
    agg2_kernel<1><<<(N + 3) / 4, 256, 0, stream>>>(
        row_ptr, col, hbuf, (const float2*)as_, (const float2*)ad_, b1, xb, N);

    // ---- GAT layer 2: in=128 -> heads=1, out=64 (MFMA transform) ----
    transform_mfma_kernel<64, 1><<<(N + 63) / 64, 256, 0, stream>>>(
        xb, Wf2, a_src2, a_dst2, hbuf, as_, ad_, N);
    agg1_kernel<<<(N + 3) / 4, 256, 0, stream>>>(
        row_ptr, col, hbuf, as_, ad_, b2, xbuf, N);

    // ---- MLP head with fused mean-pool (1 dispatch, no atomics) ----
    mlp_kernel<<<B, 256, 0, stream>>>(xbuf, batch, N, obs, Ws1, bs1, ln_g, ln_b,
                                      Ws2, bs2, Wa, ba, Wc, bc,
                                      out_logits, out_value);
}

// Round 4
// 292.850 us; speedup vs baseline: 1.1766x; 1.1766x over previous
//
#include <hip/hip_runtime.h>
#include <math.h>

// ---------------------------------------------------------------------------
// GATPolicy: 3x GATConv (with self loops) + mean-pool + MLP head.
// CSR-by-dst built with ZERO global atomics (device-scope atomicAdd on gfx950
// bypasses the non-coherent XCD L2s -> ~48MB line write-through + 14G/s cap;
// measured 56us in r1). Two-level bucket scheme, LDS atomics only:
//   P1  per-block LDS hist over bucket=dst>>8 [fused: transform0 + W pack
//       + gstart (graph-boundary scan of sorted batch)]
//   scanA  exclusive scan of histT[bucket][block]
//   P3  re-read edges, LDS rank within (block,bucket), write (src, dst&255)
//       into bucket-partitioned esrc/dsub8 (contiguous per-(block,bucket))
//   P4  ONE kernel per bucket: LDS count of dst&255 -> block scan -> row_ptr
//       -> col scatter via LDS cursors.
// Ranks are arbitrary-but-distinct, valid for order-independent aggregation.
// Requires n <= 65536 (bucket fits 8 bits x 256 entries); N=50000 here.
// MLP (with fused mean-pool) is LATENCY-OPTIMIZED (r3 lesson: 64 blocks x
// serial scalar loops = 78us at 0.7% VALU): 512 threads/block, pool reads
// ushort8 (16B) with 64 row-groups + shfl_xor reduce, gstart precomputed (no
// binary search), fc1/fc2 k-split across thread halves (chain halved, 8
// waves/CU). h stored FP8 e4m3 head-interleaved; agg inner loop 8-wide
// broadcast-consume. Inter-layer features bf16; K=128 transforms via
// mfma_f32_16x16x32_bf16. (r13 lesson: never chain blocks across XCDs.)
// ---------------------------------------------------------------------------

#define LRELU(x) ((x) > 0.f ? (x) : 0.2f * (x))

typedef short bf16x8 __attribute__((ext_vector_type(8)));
typedef unsigned short u16x8 __attribute__((ext_vector_type(8)));
typedef float f32x4 __attribute__((ext_vector_type(4)));
typedef float f32x2 __attribute__((ext_vector_type(2)));

__device__ __forceinline__ float readlane_f(float v, int lane) {
    return __int_as_float(__builtin_amdgcn_readlane(__float_as_int(v), lane));
}
__device__ __forceinline__ unsigned readlane_u(unsigned v, int lane) {
    return (unsigned)__builtin_amdgcn_readlane((int)v, lane);
}
__device__ __forceinline__ unsigned short f2bf(float f) {
    unsigned int u = __float_as_uint(f);
    u = (u + 0x7fffu + ((u >> 16) & 1u)) >> 16;  // RNE
    return (unsigned short)u;
}
__device__ __forceinline__ float bf2f(unsigned short u) {
    return __uint_as_float((unsigned int)u << 16);
}
__device__ __forceinline__ unsigned char f2fp8(float f) {
    return (unsigned char)(__builtin_amdgcn_cvt_pk_fp8_f32(f, f, 0, false) & 0xff);
}
__device__ __forceinline__ f32x2 fp8pair(unsigned int u) {
    return __builtin_amdgcn_cvt_pk_f32_fp8(u, false);  // bytes 0,1
}

// -- P1: bucket hist || layer-0 transform (K=8) || W pack || gstart ---------
// block ranges: [0,G1) hist, [G1,+t0b) transform0, [+wp) W pack, rest gstart.

__global__ __launch_bounds__(256) void hist_t0_kernel(
    const int* __restrict__ dst, int* __restrict__ histT,
    int e, int G1, int NB, int n, int hist_blocks, int t0_blocks, int wp_blocks,
    const float* __restrict__ x, const float* __restrict__ W,
    const float* __restrict__ a_src, const float* __restrict__ a_dst,
    unsigned char* __restrict__ h, float* __restrict__ as_o,
    float* __restrict__ ad_o,
    const float* __restrict__ W1, const float* __restrict__ W2,
    unsigned short* __restrict__ Wf1, unsigned short* __restrict__ Wf2,
    const int* __restrict__ batch, int* __restrict__ gstart, int nGraphs) {
    __shared__ unsigned int hist[256];
    __shared__ float xs[2][8][8];
    if ((int)blockIdx.x < hist_blocks) {
        hist[threadIdx.x] = 0;
        __syncthreads();
        int base = blockIdx.x * 2048 + threadIdx.x * 8;
        int d[8];
        if (base + 8 <= e) {
            int4 x0 = *(const int4*)(dst + base);
            int4 x1 = *(const int4*)(dst + base + 4);
            d[0] = x0.x; d[1] = x0.y; d[2] = x0.z; d[3] = x0.w;
            d[4] = x1.x; d[5] = x1.y; d[6] = x1.z; d[7] = x1.w;
        } else {
#pragma unroll
            for (int j = 0; j < 8; j++) {
                int ij = base + j;
                d[j] = (ij < e) ? dst[ij] : -1;
            }
        }
#pragma unroll
        for (int j = 0; j < 8; j++) {
            if (d[j] >= 0) atomicAdd(&hist[d[j] >> 8], 1u);
        }
        __syncthreads();
        int b = threadIdx.x;
        if (b < NB) histT[b * G1 + blockIdx.x] = (int)hist[b];
        return;
    }
    if ((int)blockIdx.x < hist_blocks + t0_blocks) {
        // ---- transform0 path: h(fp8)=x@W0, as/ad. 16 nodes/block ----
        const int bid2 = blockIdx.x - hist_blocks;
        const int tid = threadIdx.x & 127;
        const int half = threadIdx.x >> 7;
        const int node0 = bid2 * 16 + half * 8;

        for (int idx = tid; idx < 64; idx += 128) {
            int ni = idx >> 3, k = idx & 7;
            int ng = node0 + ni;
            xs[half][ni][k] = (ng < n) ? x[(size_t)ng * 8 + k] : 0.f;
        }
        __syncthreads();

        float acc[8];
#pragma unroll
        for (int i = 0; i < 8; i++) acc[i] = 0.f;
#pragma unroll
        for (int k = 0; k < 8; k++) {
            float wk = W[k * 128 + tid];
#pragma unroll
            for (int i = 0; i < 8; i++) acc[i] += xs[half][i][k] * wk;
        }

        const int lane = tid & 63;
        const int head = tid >> 6;
        const int pos = 2 * lane + head;  // 2-head interleaved fp8 byte pos
        const float av = a_src[tid];
        const float dv = a_dst[tid];
#pragma unroll
        for (int i = 0; i < 8; i++) {
            int ng = node0 + i;
            if (ng >= n) break;
            h[(size_t)ng * 128 + pos] = f2fp8(acc[i]);
            float ps = acc[i] * av, pd = acc[i] * dv;
            for (int off = 32; off; off >>= 1) {
                ps += __shfl_xor(ps, off, 64);
                pd += __shfl_xor(pd, off, 64);
            }
            if (lane == 0) {
                as_o[ng * 2 + head] = ps;
                ad_o[ng * 2 + head] = pd;
            }
        }
        return;
    }
    if ((int)blockIdx.x < hist_blocks + t0_blocks + wp_blocks) {
        // ---- W pack path ----
        const int n1 = 8 * 4 * 64;   // W1 fragment rows (OUT=128)
        const int n2 = 4 * 4 * 64;   // W2 fragment rows (OUT=64)
        int gid = (blockIdx.x - hist_blocks - t0_blocks) * 256 + threadIdx.x;
        if (gid < n1) {
            int idx = gid;
            int lane = idx & 63, ts = idx >> 6;
            int s = ts & 3, t = ts >> 2;
            int quad = lane >> 4, cn = lane & 15;
#pragma unroll
            for (int j = 0; j < 8; j++)
                Wf1[idx * 8 + j] = f2bf(W1[(s * 32 + quad * 8 + j) * 128 + t * 16 + cn]);
        } else if (gid < n1 + n2) {
            int idx = gid - n1;
            int lane = idx & 63, ts = idx >> 6;
            int s = ts & 3, t = ts >> 2;
            int quad = lane >> 4, cn = lane & 15;
#pragma unroll
            for (int j = 0; j < 8; j++)
                Wf2[idx * 8 + j] = f2bf(W2[(s * 32 + quad * 8 + j) * 64 + t * 16 + cn]);
        }
        return;
    }
    // ---- gstart path: graph boundaries of sorted batch ----
    int gid = (blockIdx.x - hist_blocks - t0_blocks - wp_blocks) * 256 + threadIdx.x;
    if (gid < n) {
        int bi = batch[gid];
        if (gid == 0) {
            for (int g = 0; g <= bi; g++) gstart[g] = 0;
        } else {
            int bp = batch[gid - 1];
            if (bi != bp)
                for (int g = bp + 1; g <= bi; g++) gstart[g] = gid;
        }
        if (gid == n - 1) {
            for (int g = bi + 1; g <= nGraphs; g++) gstart[g] = n;
        }
    }
}

// ---------------- generalized scan: 512 elements per block -----------------

__global__ __launch_bounds__(256) void scan2_block_kernel(
    const int* __restrict__ in, int* __restrict__ out,
    int* __restrict__ blockSums, int len) {
    __shared__ int lds[256];
    int t = threadIdx.x;
    int i0 = blockIdx.x * 512 + 2 * t;
    int v0 = (i0 < len) ? in[i0] : 0;
    int v1 = (i0 + 1 < len) ? in[i0 + 1] : 0;
    int s = v0 + v1;
    lds[t] = s;
    __syncthreads();
    for (int off = 1; off < 256; off <<= 1) {
        int u = (t >= off) ? lds[t - off] : 0;
        __syncthreads();
        lds[t] += u;
        __syncthreads();
    }
    int base = lds[t] - s;  // block-local exclusive for element i0
    if (i0 < len) out[i0] = base;
    if (i0 + 1 < len) out[i0 + 1] = base + v0;
    if (t == 255) blockSums[blockIdx.x] = lds[255];
}

// Every block redundantly scans blockSums (nb <= 256) and applies its base.
// Also writes out[len] = total.
__global__ __launch_bounds__(256) void scan2_finalize_kernel(
    int* __restrict__ out, const int* __restrict__ blockSums, int len, int nb) {
    __shared__ int lds[256];
    int t = threadIdx.x;
    int v = (t < nb) ? blockSums[t] : 0;
    lds[t] = v;
    __syncthreads();
    for (int off = 1; off < 256; off <<= 1) {
        int u = (t >= off) ? lds[t - off] : 0;
        __syncthreads();
        lds[t] += u;
        __syncthreads();
    }
    const int bid = blockIdx.x;
    const int base = (bid > 0) ? lds[bid - 1] : 0;
    const int total = lds[nb - 1];
    int i0 = bid * 512 + 2 * t;
#pragma unroll
    for (int q = 0; q < 2; q++) {
        int i = i0 + q;
        if (i < len) out[i] += base;
        else if (i == len) out[len] = total;
    }
}

// ---------------- P3: bucket partition (LDS ranks, no global atomics) ------

__global__ __launch_bounds__(256) void bucket_scatter_kernel(
    const int* __restrict__ src, const int* __restrict__ dst,
    const int* __restrict__ offs, int* __restrict__ esrc,
    unsigned char* __restrict__ dsub8, int e, int G1) {
    __shared__ unsigned int hist[256];
    hist[threadIdx.x] = 0;
    __syncthreads();
    int base = blockIdx.x * 2048 + threadIdx.x * 8;
    int d[8], s[8];
    if (base + 8 <= e) {
        int4 d0 = *(const int4*)(dst + base);
        int4 d1 = *(const int4*)(dst + base + 4);
        int4 s0 = *(const int4*)(src + base);
        int4 s1 = *(const int4*)(src + base + 4);
        d[0] = d0.x; d[1] = d0.y; d[2] = d0.z; d[3] = d0.w;
        d[4] = d1.x; d[5] = d1.y; d[6] = d1.z; d[7] = d1.w;
        s[0] = s0.x; s[1] = s0.y; s[2] = s0.z; s[3] = s0.w;
        s[4] = s1.x; s[5] = s1.y; s[6] = s1.z; s[7] = s1.w;
    } else {
#pragma unroll
        for (int j = 0; j < 8; j++) {
            int ij = base + j;
            bool v = ij < e;
            d[j] = v ? dst[ij] : -1;
            s[j] = v ? src[ij] : 0;
        }
    }
    unsigned lr[8];
#pragma unroll
    for (int j = 0; j < 8; j++) {
        lr[j] = (d[j] >= 0) ? atomicAdd(&hist[d[j] >> 8], 1u) : 0u;
    }
#pragma unroll
    for (int j = 0; j < 8; j++) {
        if (d[j] >= 0) {
            int pos = offs[(d[j] >> 8) * G1 + blockIdx.x] + (int)lr[j];
            esrc[pos] = s[j];
            dsub8[pos] = (unsigned char)(d[j] & 255);
        }
    }
}

// -------- P4: per-bucket CSR finalize: count -> scan -> row_ptr -> col -----

__global__ __launch_bounds__(256) void bucket_csr_kernel(
    const int* __restrict__ offs, const unsigned char* __restrict__ dsub8,
    const int* __restrict__ esrc, int* __restrict__ row_ptr,
    int* __restrict__ col, int G1, int n) {
    __shared__ unsigned int cnt[256];
    __shared__ int rp[256];
    int t = threadIdx.x;
    int b = blockIdx.x;
    cnt[t] = 0;
    __syncthreads();
    int bs = offs[b * G1];
    int be = offs[(b + 1) * G1];
    for (int i = bs + t; i < be; i += 256) {
        atomicAdd(&cnt[dsub8[i]], 1u);
    }
    __syncthreads();
    int v = (int)cnt[t];
    rp[t] = v;
    __syncthreads();
    for (int off = 1; off < 256; off <<= 1) {
        int u = (t >= off) ? rp[t - off] : 0;
        __syncthreads();
        rp[t] += u;
        __syncthreads();
    }
    int excl = rp[t] - v;
    int node = b * 256 + t;
    if (node <= n) row_ptr[node] = bs + excl;  // node==n lands here too (E)
    __syncthreads();
    cnt[t] = (unsigned)excl;  // running cursors
    __syncthreads();
    for (int i = bs + t; i < be; i += 256) {
        int sub = dsub8[i];
        unsigned r = atomicAdd(&cnt[sub], 1u);
        col[bs + (int)r] = esrc[i];
    }
}

// fp8 h byte position for channel c: 2-head interleaved pairs, 1-head flat
template <int OUT, int HEADS>
__device__ __forceinline__ int hpos8(int c) {
    return (HEADS == 2) ? (2 * (c & 63) + (c >> 6)) : c;
}

// ---------------- MFMA transform (K=128): h(fp8)=xb(bf16)@W, as/ad ---------

template <int OUT, int HEADS>
__global__ __launch_bounds__(256) void transform_mfma_kernel(
    const unsigned short* __restrict__ xb, const unsigned short* __restrict__ Wf,
    const float* __restrict__ a_src, const float* __restrict__ a_dst,
    unsigned char* __restrict__ h, float* __restrict__ as_o, float* __restrict__ ad_o,
    int n) {
    constexpr int T = OUT / 16, S = 4;  // K = 128
    const int w = threadIdx.x >> 6, lane = threadIdx.x & 63;
    const int node0 = (blockIdx.x * 4 + w) * 16;
    if (node0 >= n) return;
    const int quad = lane >> 4, col = lane & 15;

    const int arow = node0 + col;
    const bool aok = arow < n;
    bf16x8 a[S];
    const unsigned short* xrow = xb + (size_t)arow * 128 + quad * 8;
#pragma unroll
    for (int s = 0; s < S; s++) {
        bf16x8 z = {0, 0, 0, 0, 0, 0, 0, 0};
        a[s] = aok ? *(const bf16x8*)(xrow + s * 32) : z;
    }

    f32x4 acc[T];
#pragma unroll
    for (int t = 0; t < T; t++) acc[t] = (f32x4){0.f, 0.f, 0.f, 0.f};

#pragma unroll
    for (int s = 0; s < S; s++) {
#pragma unroll
        for (int t = 0; t < T; t++) {
            bf16x8 b = *(const bf16x8*)(Wf + ((size_t)(t * S + s) * 64 + lane) * 8);
            acc[t] = __builtin_amdgcn_mfma_f32_16x16x32_bf16(a[s], b, acc[t], 0, 0, 0);
        }
    }

#pragma unroll
    for (int t = 0; t < T; t++) {
        int pos = hpos8<OUT, HEADS>(t * 16 + col);
#pragma unroll
        for (int r = 0; r < 4; r++) {
            int m = node0 + quad * 4 + r;
            if (m < n) h[(size_t)m * OUT + pos] = f2fp8(acc[t][r]);
        }
    }

#pragma unroll
    for (int r = 0; r < 4; r++) {
        float s0 = 0.f, s1 = 0.f, d0 = 0.f, d1 = 0.f;
#pragma unroll
        for (int t = 0; t < T; t++) {
            float av = a_src[t * 16 + col];
            float dv = a_dst[t * 16 + col];
            float v = acc[t][r];
            if (HEADS == 2 && t >= T / 2) { s1 += v * av; d1 += v * dv; }
            else                          { s0 += v * av; d0 += v * dv; }
        }
        for (int off = 8; off; off >>= 1) {
            s0 += __shfl_xor(s0, off, 64);
            d0 += __shfl_xor(d0, off, 64);
            if (HEADS == 2) {
                s1 += __shfl_xor(s1, off, 64);
                d1 += __shfl_xor(d1, off, 64);
            }
        }
        int m = node0 + quad * 4 + r;
        if (m < n) {
            if (HEADS == 2) {
                if (col == 0)      { as_o[m * 2] = s0;     ad_o[m * 2] = d0; }
                else if (col == 1) { as_o[m * 2 + 1] = s1; ad_o[m * 2 + 1] = d1; }
            } else {
                if (col == 0) { as_o[m] = s0; ad_o[m] = d0; }
            }
        }
    }
}

// ---------------- GAT aggregation, 2 heads (fp8 h): one wave per node ------
// 8-wide serial consume: all 8 gather loads issue before the w broadcasts.

template <int ACT>  // 1 = elu
__global__ __launch_bounds__(256) void agg2_kernel(
    const int* __restrict__ row_ptr, const int* __restrict__ col,
    const unsigned char* __restrict__ h, const float2* __restrict__ as2,
    const float2* __restrict__ ad2, const float* __restrict__ bias,
    unsigned short* __restrict__ out, int n) {
    const int node = blockIdx.x * 4 + (threadIdx.x >> 6);
    const int lane = threadIdx.x & 63;
    if (node >= n) return;

    const int beg = row_ptr[node], end = row_ptr[node + 1];
    const float2 adv = ad2[node];
    const unsigned char* __restrict__ hb = h + 2 * lane;

    // self-loop
    const float2 avs = as2[node];
    float w0s = __expf(LRELU(avs.x + adv.x));
    float w1s = __expf(LRELU(avs.y + adv.y));
    unsigned int us = *(const unsigned short*)(hb + ((size_t)node << 7));
    f32x2 hvs = fp8pair(us);
    float accL = w0s * hvs.x, accH = w1s * hvs.y;
    float den0 = w0s, den1 = w1s;

    for (int base = beg; base < end; base += 64) {
        int cnt = end - base;
        if (cnt > 64) cnt = 64;
        int s = 0;
        float w0 = 0.f, w1 = 0.f;
        if (lane < cnt) {
            s = col[base + lane];
            float2 av = as2[s];
            w0 = __expf(LRELU(av.x + adv.x));
            w1 = __expf(LRELU(av.y + adv.y));
        }
        float t0 = w0, t1 = w1;
        for (int off = 32; off; off >>= 1) {
            t0 += __shfl_xor(t0, off, 64);
            t1 += __shfl_xor(t1, off, 64);
        }
        den0 += t0;
        den1 += t1;

        unsigned soff = (unsigned)s << 7;  // row byte offset (128 B)
        for (int j = 0; j < cnt; j += 8) {  // j <= 56; pads carry w=0
            unsigned o0 = readlane_u(soff, j);
            unsigned o1 = readlane_u(soff, j + 1);
            unsigned o2 = readlane_u(soff, j + 2);
            unsigned o3 = readlane_u(soff, j + 3);
            unsigned o4 = readlane_u(soff, j + 4);
            unsigned o5 = readlane_u(soff, j + 5);
            unsigned o6 = readlane_u(soff, j + 6);
            unsigned o7 = readlane_u(soff, j + 7);
            unsigned u0 = *(const unsigned short*)(hb + o0);
            unsigned u1 = *(const unsigned short*)(hb + o1);
            unsigned u2 = *(const unsigned short*)(hb + o2);
            unsigned u3 = *(const unsigned short*)(hb + o3);
            unsigned u4 = *(const unsigned short*)(hb + o4);
            unsigned u5 = *(const unsigned short*)(hb + o5);
            unsigned u6 = *(const unsigned short*)(hb + o6);
            unsigned u7 = *(const unsigned short*)(hb + o7);
            float a0 = readlane_f(w0, j),     a1 = readlane_f(w1, j);
            float b0 = readlane_f(w0, j + 1), b1 = readlane_f(w1, j + 1);
            float c0 = readlane_f(w0, j + 2), c1 = readlane_f(w1, j + 2);
            float d0 = readlane_f(w0, j + 3), d1 = readlane_f(w1, j + 3);
            float e0 = readlane_f(w0, j + 4), e1 = readlane_f(w1, j + 4);
            float f0 = readlane_f(w0, j + 5), f1 = readlane_f(w1, j + 5);
            float g0 = readlane_f(w0, j + 6), g1 = readlane_f(w1, j + 6);
            float i0 = readlane_f(w0, j + 7), i1 = readlane_f(w1, j + 7);
            f32x2 hA = fp8pair(u0);
            f32x2 hB = fp8pair(u1);
            f32x2 hC = fp8pair(u2);
            f32x2 hD = fp8pair(u3);
            f32x2 hE = fp8pair(u4);
            f32x2 hF = fp8pair(u5);
            f32x2 hG = fp8pair(u6);
            f32x2 hH = fp8pair(u7);
            accL += a0 * hA.x; accH += a1 * hA.y;
            accL += b0 * hB.x; accH += b1 * hB.y;
            accL += c0 * hC.x; accH += c1 * hC.y;
            accL += d0 * hD.x; accH += d1 * hD.y;
            accL += e0 * hE.x; accH += e1 * hE.y;
            accL += f0 * hF.x; accH += f1 * hF.y;
            accL += g0 * hG.x; accH += g1 * hG.y;
            accL += i0 * hH.x; accH += i1 * hH.y;
        }
    }

    float oL = accL / (den0 + 1e-16f) + bias[lane];
    float oH = accH / (den1 + 1e-16f) + bias[64 + lane];
    if (ACT) {
        oL = oL > 0.f ? oL : expm1f(oL);
        oH = oH > 0.f ? oH : expm1f(oH);
    }
    out[(size_t)node * 128 + lane] = f2bf(oL);
    out[(size_t)node * 128 + 64 + lane] = f2bf(oH);
}

// ---------------- GAT aggregation, 1 head (fp8 h, layer 2) -----------------
// Output bf16 (feeds pool only).

__global__ __launch_bounds__(256) void agg1_kernel(
    const int* __restrict__ row_ptr, const int* __restrict__ col,
    const unsigned char* __restrict__ h, const float* __restrict__ as1,
    const float* __restrict__ ad1, const float* __restrict__ bias,
    unsigned short* __restrict__ out, int n) {
    const int node = blockIdx.x * 4 + (threadIdx.x >> 6);
    const int lane = threadIdx.x & 63;
    if (node >= n) return;

    const int beg = row_ptr[node], end = row_ptr[node + 1];
    const float adv = ad1[node];
    const unsigned char* __restrict__ hb = h + lane;

    float ws = __expf(LRELU(as1[node] + adv));
    float acc = ws * fp8pair((unsigned)hb[(size_t)node << 6]).x;
    float den = ws;

    for (int base = beg; base < end; base += 64) {
        int cnt = end - base;
        if (cnt > 64) cnt = 64;
        int s = 0;
        float w = 0.f;
        if (lane < cnt) {
            s = col[base + lane];
            w = __expf(LRELU(as1[s] + adv));
        }
        float t = w;
        for (int off = 32; off; off >>= 1) t += __shfl_xor(t, off, 64);
        den += t;

        unsigned soff = (unsigned)s << 6;  // row byte offset (64 B)
        for (int j = 0; j < cnt; j += 8) {
            unsigned o0 = readlane_u(soff, j);
            unsigned o1 = readlane_u(soff, j + 1);
            unsigned o2 = readlane_u(soff, j + 2);
            unsigned o3 = readlane_u(soff, j + 3);
            unsigned o4 = readlane_u(soff, j + 4);
            unsigned o5 = readlane_u(soff, j + 5);
            unsigned o6 = readlane_u(soff, j + 6);
            unsigned o7 = readlane_u(soff, j + 7);
            unsigned u0 = hb[o0];
            unsigned u1 = hb[o1];
            unsigned u2 = hb[o2];
            unsigned u3 = hb[o3];
            unsigned u4 = hb[o4];
            unsigned u5 = hb[o5];
            unsigned u6 = hb[o6];
            unsigned u7 = hb[o7];
            float wA = readlane_f(w, j);
            float wB = readlane_f(w, j + 1);
            float wC = readlane_f(w, j + 2);
            float wD = readlane_f(w, j + 3);
            float wE = readlane_f(w, j + 4);
            float wF = readlane_f(w, j + 5);
            float wG = readlane_f(w, j + 6);
            float wH = readlane_f(w, j + 7);
            acc += wA * fp8pair(u0).x;
            acc += wB * fp8pair(u1).x;
            acc += wC * fp8pair(u2).x;
            acc += wD * fp8pair(u3).x;
            acc += wE * fp8pair(u4).x;
            acc += wF * fp8pair(u5).x;
            acc += wG * fp8pair(u6).x;
            acc += wH * fp8pair(u7).x;
        }
    }

    out[(size_t)node * 64 + lane] = f2bf(acc / (den + 1e-16f) + bias[lane]);
}

// ------- MLP head (pool fused): 512 threads/block, one block per graph -----
// Pool: 64 row-groups x 8 ushort8-chunks (16B loads), shfl_xor reduce.
// fc1/fc2: k-loop split across thread halves (t and t+256), LDS combine.

__global__ __launch_bounds__(512) void mlp_kernel(
    const unsigned short* __restrict__ xbuf, const int* __restrict__ gstart,
    const float* __restrict__ obs,
    const float* __restrict__ Ws1, const float* __restrict__ bs1,
    const float* __restrict__ ln_g, const float* __restrict__ ln_b,
    const float* __restrict__ Ws2, const float* __restrict__ bs2,
    const float* __restrict__ Wa, const float* __restrict__ ba,
    const float* __restrict__ Wc, const float* __restrict__ bc,
    float* __restrict__ out_logits, float* __restrict__ out_value) {
    int b = blockIdx.x;
    int t = threadIdx.x;
    __shared__ float comb[192];
    __shared__ float red[512];
    __shared__ float red2[8][64];
    __shared__ float hs[256];

    const int gs = gstart[b];
    const int ge = gstart[b + 1];

    // ---- pool: 64 rowgroups (8/wave) x 8 chunks of ushort8 ----
    {
        const int w = t >> 6, lane = t & 63;
        const int rg = w * 8 + (lane >> 3);   // global row-group 0..63
        const int sub = lane & 7;             // 8 ushort chunk
        float acc[8];
#pragma unroll
        for (int j = 0; j < 8; j++) acc[j] = 0.f;
        for (int i = gs + rg; i < ge; i += 64) {
            u16x8 v = *(const u16x8*)(xbuf + (size_t)i * 64 + sub * 8);
#pragma unroll
            for (int j = 0; j < 8; j++) acc[j] += bf2f(v[j]);
        }
        // reduce over the 8 wave-local rowgroups (lane bits 3..5)
#pragma unroll
        for (int off = 8; off <= 32; off <<= 1) {
#pragma unroll
            for (int j = 0; j < 8; j++) acc[j] += __shfl_xor(acc[j], off, 64);
        }
        if (lane < 8) {
#pragma unroll
            for (int j = 0; j < 8; j++) red2[w][lane * 8 + j] = acc[j];
        }
    }
    __syncthreads();
    {
        float cdiv = fmaxf((float)(ge - gs), 1.f);
        if (t < 64) {
            float s = 0.f;
#pragma unroll
            for (int w = 0; w < 8; w++) s += red2[w][t];
            comb[t] = s / cdiv;
        } else if (t < 192) {
            comb[t] = obs[b * 128 + (t - 64)];
        }
    }
    __syncthreads();

    const int t256 = t & 255;
    const int khalf = t >> 8;

    // ---- fc1: k split 2x96 ----
    {
        float accA = 0.f, accB = 0.f;
        int k0 = khalf * 96;
#pragma unroll 4
        for (int k = k0; k < k0 + 96; k += 2) {
            accA += comb[k] * Ws1[k * 256 + t256];
            accB += comb[k + 1] * Ws1[(k + 1) * 256 + t256];
        }
        red[t] = accA + accB;
    }
    __syncthreads();
    float acc = 0.f;
    if (t < 256) acc = bs1[t] + red[t] + red[t + 256];
    __syncthreads();

    // ---- LayerNorm over 256 (first 256 threads carry values) ----
    red[t] = (t < 256) ? acc : 0.f;
    __syncthreads();
    for (int off = 128; off; off >>= 1) {
        if (t < off) red[t] += red[t + off];
        __syncthreads();
    }
    float mu = red[0] / 256.f;
    __syncthreads();
    float d = acc - mu;
    red[t] = (t < 256) ? d * d : 0.f;
    __syncthreads();
    for (int off = 128; off; off >>= 1) {
        if (t < off) red[t] += red[t + off];
        __syncthreads();
    }
    float var = red[0] / 256.f;
    if (t < 256) {
        float hn = d * rsqrtf(var + 1e-5f) * ln_g[t] + ln_b[t];
        hs[t] = hn > 0.f ? hn : 0.f;
    }
    __syncthreads();

    // ---- fc2: k split 2x128 ----
    {
        float a2A = 0.f, a2B = 0.f;
        int k0 = khalf * 128;
#pragma unroll 4
        for (int k = k0; k < k0 + 128; k += 2) {
            a2A += hs[k] * Ws2[k * 256 + t256];
            a2B += hs[k + 1] * Ws2[(k + 1) * 256 + t256];
        }
        red[t] = a2A + a2B;
    }
    __syncthreads();
    float acc2 = 0.f;
    if (t < 256) {
        acc2 = bs2[t] + red[t] + red[t + 256];
        acc2 = acc2 > 0.f ? acc2 : 0.f;
    }
    __syncthreads();
    if (t < 256) hs[t] = acc2;
    __syncthreads();

    // ---- logits: 16 outs x 32 k-chunks of 8 + LDS tree ----
    {
        int o = t & 15, ck = t >> 4;  // ck in [0,32)
        float p = 0.f;
#pragma unroll
        for (int k = 0; k < 8; k++)
            p += hs[ck * 8 + k] * Wa[(ck * 8 + k) * 16 + o];
        red[t] = p;
    }
    __syncthreads();
    for (int off = 16; off >= 1; off >>= 1) {
        if ((t >> 4) < off) red[t] += red[t + off * 16];
        __syncthreads();
    }
    if (t < 16) out_logits[b * 16 + t] = red[t] + ba[t];
    __syncthreads();

    // ---- value: full-width dot + tree over 512 ----
    red[t] = (t < 256) ? hs[t] * Wc[t] : 0.f;
    __syncthreads();
    for (int off = 256; off; off >>= 1) {
        if (t < off) red[t] += red[t + off];
        __syncthreads();
    }
    if (t == 0) out_value[b] = red[0] + bc[0];
}

// ---------------------------------------------------------------------------

extern "C" void kernel_launch(void* const* d_in, const int* in_sizes, int n_in,
                              void* d_out, int out_size, void* d_ws, size_t ws_size,
                              hipStream_t stream) {
    const float* obs    = (const float*)d_in[0];
    const float* nf     = (const float*)d_in[1];
    const int*   ei     = (const int*)d_in[2];
    const int*   batch  = (const int*)d_in[3];
    const float* W0     = (const float*)d_in[4];
    const float* a_src0 = (const float*)d_in[5];
    const float* a_dst0 = (const float*)d_in[6];
    const float* b0     = (const float*)d_in[7];
    const float* W1     = (const float*)d_in[8];
    const float* a_src1 = (const float*)d_in[9];
    const float* a_dst1 = (const float*)d_in[10];
    const float* b1     = (const float*)d_in[11];
    const float* W2     = (const float*)d_in[12];
    const float* a_src2 = (const float*)d_in[13];
    const float* a_dst2 = (const float*)d_in[14];
    const float* b2     = (const float*)d_in[15];
    const float* Ws1    = (const float*)d_in[16];
    const float* bs1    = (const float*)d_in[17];
    const float* ln_g   = (const float*)d_in[18];
    const float* ln_b   = (const float*)d_in[19];
    const float* Ws2    = (const float*)d_in[20];
    const float* bs2    = (const float*)d_in[21];
    const float* Wa     = (const float*)d_in[22];
    const float* ba     = (const float*)d_in[23];
    const float* Wc     = (const float*)d_in[24];
    const float* bc     = (const float*)d_in[25];

    const int N = in_sizes[3];
    const int E = in_sizes[2] / 2;
    const int B = in_sizes[0] / 128;
    const int* src = ei;
    const int* dstp = ei + E;

    // workspace carve (256B aligned)
    char* p = (char*)d_ws;
    auto alloc = [&](size_t bytes) -> void* {
        void* r = (void*)p;
        p += (bytes + 255) & ~(size_t)255;
        return r;
    };
    const int G1 = (E + 2047) / 2048;       // edge chunks (2048/block)
    const int NB = (N + 255) >> 8;          // dst buckets (n <= 65536)
    const int L  = NB * G1;                 // histT length
    int*   row_ptr   = (int*)alloc((size_t)(N + 1) * 4);
    int*   col       = (int*)alloc((size_t)E * 4);
    int*   esrc      = (int*)alloc((size_t)E * 4);           // bucketed src
    unsigned char* dsub8 = (unsigned char*)alloc((size_t)E); // bucketed dst&255
    int*   histT     = (int*)alloc((size_t)L * 4);
    int*   offs      = (int*)alloc((size_t)(L + 1) * 4);
    unsigned char* hbuf = (unsigned char*)alloc((size_t)N * 128);       // fp8 interleaved
    unsigned short* xb = (unsigned short*)alloc((size_t)N * 128 * 2);   // bf16 features
    unsigned short* xbuf = (unsigned short*)alloc((size_t)N * 64 * 2);  // final layer bf16
    float* as_       = (float*)alloc((size_t)N * 2 * 4);
    float* ad_       = (float*)alloc((size_t)N * 2 * 4);
    unsigned short* Wf1 = (unsigned short*)alloc((size_t)8 * 4 * 64 * 8 * 2);
    unsigned short* Wf2 = (unsigned short*)alloc((size_t)4 * 4 * 64 * 8 * 2);
    int* gstart      = (int*)alloc((size_t)(B + 1) * 4);
    // scratch (blockSums) aliases xb region: scanA completes (stream-ordered)
    // before xb's first write (agg2, layer 0).
    int* blockSums = (int*)xb;   // up to 256 entries

    float* out_logits = (float*)d_out;
    float* out_value  = out_logits + (size_t)B * 16;

    // ---- P1: hist || transform0 || W pack || gstart (1 dispatch) ----
    int t0_blocks = (N + 15) / 16;
    int wp_blocks = (8 * 4 * 64 + 4 * 4 * 64 + 255) / 256;
    int gb_blocks = (N + 255) / 256;
    hist_t0_kernel<<<G1 + t0_blocks + wp_blocks + gb_blocks, 256, 0, stream>>>(
        dstp, histT, E, G1, NB, N, G1, t0_blocks, wp_blocks,
        nf, W0, a_src0, a_dst0, hbuf, as_, ad_,
        W1, W2, Wf1, Wf2, batch, gstart, B);

    // ---- scanA over histT -> offs ----
    int nbA = (L + 511) / 512;
    scan2_block_kernel<<<nbA, 256, 0, stream>>>(histT, offs, blockSums, L);
    scan2_finalize_kernel<<<(L + 1 + 511) / 512, 256, 0, stream>>>(offs, blockSums, L, nbA);

    // ---- P3 bucket partition + P4 per-bucket CSR finalize ----
    bucket_scatter_kernel<<<G1, 256, 0, stream>>>(src, dstp, offs, esrc, dsub8, E, G1);
    bucket_csr_kernel<<<NB, 256, 0, stream>>>(offs, dsub8, esrc, row_ptr, col, G1, N);

    // ---- GAT layer 0 aggregation (transform fused into P1) ----
    agg2_kernel<1><<<(N + 3) / 4, 256, 0, stream>>>(
        row_ptr, col, hbuf, (const float2*)as_, (const float2*)ad_, b0, xb, N);

    // ---- GAT layer 1: in=128 -> concat, elu (MFMA transform) ----
    transform_mfma_kernel<128, 2><<<(N + 63) / 64, 256, 0, stream>>>(
        xb, Wf1, a_src1, a_dst1, hbuf, as_, ad_, N);
    agg2_kernel<1><<<(N + 3) / 4, 256, 0, stream>>>(
        row_ptr, col, hbuf, (const float2*)as_, (const float2*)ad_, b1, xb, N);

    // ---- GAT layer 2: in=128 -> heads=1, out=64 (MFMA transform) ----
    transform_mfma_kernel<64, 1><<<(N + 63) / 64, 256, 0, stream>>>(
        xb, Wf2, a_src2, a_dst2, hbuf, as_, ad_, N);
    agg1_kernel<<<(N + 3) / 4, 256, 0, stream>>>(
        row_ptr, col, hbuf, as_, ad_, b2, xbuf, N);

    // ---- MLP head with fused mean-pool (1 dispatch, no atomics) ----
    mlp_kernel<<<B, 512, 0, stream>>>(xbuf, gstart, obs, Ws1, bs1, ln_g, ln_b,
                                      Ws2, bs2, Wa, ba, Wc, bc,
                                      out_logits, out_value);
}

// Round 5
// 265.467 us; speedup vs baseline: 1.2980x; 1.1032x over previous
//
#include <hip/hip_runtime.h>
#include <math.h>

// ---------------------------------------------------------------------------
// GATPolicy: 3x GATConv (with self loops) + mean-pool + MLP head.
// CSR-by-dst built with ZERO global atomics (device-scope atomicAdd on gfx950
// bypasses the non-coherent XCD L2s; measured 56us in r1). Two-level bucket
// scheme, LDS atomics only (P1 hist -> scanA -> P3 partition -> P4 per-bucket
// count/scan/row_ptr/col). Ranks arbitrary-but-distinct (order-independent
// aggregation). Requires n <= 65536. N=50000 here.
// AGG (r4 lesson: one-wave-per-node + readlane broadcast-consume wastes 75%
// of lanes at avg deg=16): 2 nodes PER WAVE — each 32-lane half owns a node;
// lane l gathers a dword (= channels 2l,2l+1 x 2 heads of the fp8-interleaved
// row); 32-edge chunks compute weights at full lane utilization, stage
// {w0,w1,rowoff} to wave-private LDS, consume as uniform-per-half broadcast
// reads (2-addr LDS = conflict-free) with 8 loads in flight.
// MLP (with fused mean-pool): 512 thr/block, ushort8 pool loads, gstart
// precomputed in P1, fc k-split across thread halves (r3 lesson).
// Inter-layer features bf16; K=128 transforms via mfma_f32_16x16x32_bf16.
// (r13 lesson: never chain blocks across XCDs.)
// ---------------------------------------------------------------------------

#define LRELU(x) ((x) > 0.f ? (x) : 0.2f * (x))

typedef short bf16x8 __attribute__((ext_vector_type(8)));
typedef unsigned short u16x8 __attribute__((ext_vector_type(8)));
typedef float f32x4 __attribute__((ext_vector_type(4)));
typedef float f32x2 __attribute__((ext_vector_type(2)));

__device__ __forceinline__ unsigned short f2bf(float f) {
    unsigned int u = __float_as_uint(f);
    u = (u + 0x7fffu + ((u >> 16) & 1u)) >> 16;  // RNE
    return (unsigned short)u;
}
__device__ __forceinline__ float bf2f(unsigned short u) {
    return __uint_as_float((unsigned int)u << 16);
}
__device__ __forceinline__ unsigned char f2fp8(float f) {
    return (unsigned char)(__builtin_amdgcn_cvt_pk_fp8_f32(f, f, 0, false) & 0xff);
}
__device__ __forceinline__ f32x2 fp8pair(unsigned int u) {
    return __builtin_amdgcn_cvt_pk_f32_fp8(u, false);  // bytes 0,1
}

// -- P1: bucket hist || layer-0 transform (K=8) || W pack || gstart ---------

__global__ __launch_bounds__(256) void hist_t0_kernel(
    const int* __restrict__ dst, int* __restrict__ histT,
    int e, int G1, int NB, int n, int hist_blocks, int t0_blocks, int wp_blocks,
    const float* __restrict__ x, const float* __restrict__ W,
    const float* __restrict__ a_src, const float* __restrict__ a_dst,
    unsigned char* __restrict__ h, float* __restrict__ as_o,
    float* __restrict__ ad_o,
    const float* __restrict__ W1, const float* __restrict__ W2,
    unsigned short* __restrict__ Wf1, unsigned short* __restrict__ Wf2,
    const int* __restrict__ batch, int* __restrict__ gstart, int nGraphs) {
    __shared__ unsigned int hist[256];
    __shared__ float xs[2][8][8];
    if ((int)blockIdx.x < hist_blocks) {
        hist[threadIdx.x] = 0;
        __syncthreads();
        int base = blockIdx.x * 2048 + threadIdx.x * 8;
        int d[8];
        if (base + 8 <= e) {
            int4 x0 = *(const int4*)(dst + base);
            int4 x1 = *(const int4*)(dst + base + 4);
            d[0] = x0.x; d[1] = x0.y; d[2] = x0.z; d[3] = x0.w;
            d[4] = x1.x; d[5] = x1.y; d[6] = x1.z; d[7] = x1.w;
        } else {
#pragma unroll
            for (int j = 0; j < 8; j++) {
                int ij = base + j;
                d[j] = (ij < e) ? dst[ij] : -1;
            }
        }
#pragma unroll
        for (int j = 0; j < 8; j++) {
            if (d[j] >= 0) atomicAdd(&hist[d[j] >> 8], 1u);
        }
        __syncthreads();
        int b = threadIdx.x;
        if (b < NB) histT[b * G1 + blockIdx.x] = (int)hist[b];
        return;
    }
    if ((int)blockIdx.x < hist_blocks + t0_blocks) {
        // ---- transform0 path: h(fp8)=x@W0, as/ad. 16 nodes/block ----
        const int bid2 = blockIdx.x - hist_blocks;
        const int tid = threadIdx.x & 127;
        const int half = threadIdx.x >> 7;
        const int node0 = bid2 * 16 + half * 8;

        for (int idx = tid; idx < 64; idx += 128) {
            int ni = idx >> 3, k = idx & 7;
            int ng = node0 + ni;
            xs[half][ni][k] = (ng < n) ? x[(size_t)ng * 8 + k] : 0.f;
        }
        __syncthreads();

        float acc[8];
#pragma unroll
        for (int i = 0; i < 8; i++) acc[i] = 0.f;
#pragma unroll
        for (int k = 0; k < 8; k++) {
            float wk = W[k * 128 + tid];
#pragma unroll
            for (int i = 0; i < 8; i++) acc[i] += xs[half][i][k] * wk;
        }

        const int lane = tid & 63;
        const int head = tid >> 6;
        const int pos = 2 * lane + head;  // 2-head interleaved fp8 byte pos
        const float av = a_src[tid];
        const float dv = a_dst[tid];
#pragma unroll
        for (int i = 0; i < 8; i++) {
            int ng = node0 + i;
            if (ng >= n) break;
            h[(size_t)ng * 128 + pos] = f2fp8(acc[i]);
            float ps = acc[i] * av, pd = acc[i] * dv;
            for (int off = 32; off; off >>= 1) {
                ps += __shfl_xor(ps, off, 64);
                pd += __shfl_xor(pd, off, 64);
            }
            if (lane == 0) {
                as_o[ng * 2 + head] = ps;
                ad_o[ng * 2 + head] = pd;
            }
        }
        return;
    }
    if ((int)blockIdx.x < hist_blocks + t0_blocks + wp_blocks) {
        // ---- W pack path ----
        const int n1 = 8 * 4 * 64;   // W1 fragment rows (OUT=128)
        const int n2 = 4 * 4 * 64;   // W2 fragment rows (OUT=64)
        int gid = (blockIdx.x - hist_blocks - t0_blocks) * 256 + threadIdx.x;
        if (gid < n1) {
            int idx = gid;
            int lane = idx & 63, ts = idx >> 6;
            int s = ts & 3, t = ts >> 2;
            int quad = lane >> 4, cn = lane & 15;
#pragma unroll
            for (int j = 0; j < 8; j++)
                Wf1[idx * 8 + j] = f2bf(W1[(s * 32 + quad * 8 + j) * 128 + t * 16 + cn]);
        } else if (gid < n1 + n2) {
            int idx = gid - n1;
            int lane = idx & 63, ts = idx >> 6;
            int s = ts & 3, t = ts >> 2;
            int quad = lane >> 4, cn = lane & 15;
#pragma unroll
            for (int j = 0; j < 8; j++)
                Wf2[idx * 8 + j] = f2bf(W2[(s * 32 + quad * 8 + j) * 64 + t * 16 + cn]);
        }
        return;
    }
    // ---- gstart path: graph boundaries of sorted batch ----
    int gid = (blockIdx.x - hist_blocks - t0_blocks - wp_blocks) * 256 + threadIdx.x;
    if (gid < n) {
        int bi = batch[gid];
        if (gid == 0) {
            for (int g = 0; g <= bi; g++) gstart[g] = 0;
        } else {
            int bp = batch[gid - 1];
            if (bi != bp)
                for (int g = bp + 1; g <= bi; g++) gstart[g] = gid;
        }
        if (gid == n - 1) {
            for (int g = bi + 1; g <= nGraphs; g++) gstart[g] = n;
        }
    }
}

// ---------------- generalized scan: 512 elements per block -----------------

__global__ __launch_bounds__(256) void scan2_block_kernel(
    const int* __restrict__ in, int* __restrict__ out,
    int* __restrict__ blockSums, int len) {
    __shared__ int lds[256];
    int t = threadIdx.x;
    int i0 = blockIdx.x * 512 + 2 * t;
    int v0 = (i0 < len) ? in[i0] : 0;
    int v1 = (i0 + 1 < len) ? in[i0 + 1] : 0;
    int s = v0 + v1;
    lds[t] = s;
    __syncthreads();
    for (int off = 1; off < 256; off <<= 1) {
        int u = (t >= off) ? lds[t - off] : 0;
        __syncthreads();
        lds[t] += u;
        __syncthreads();
    }
    int base = lds[t] - s;  // block-local exclusive for element i0
    if (i0 < len) out[i0] = base;
    if (i0 + 1 < len) out[i0 + 1] = base + v0;
    if (t == 255) blockSums[blockIdx.x] = lds[255];
}

// Every block redundantly scans blockSums (nb <= 256) and applies its base.
__global__ __launch_bounds__(256) void scan2_finalize_kernel(
    int* __restrict__ out, const int* __restrict__ blockSums, int len, int nb) {
    __shared__ int lds[256];
    int t = threadIdx.x;
    int v = (t < nb) ? blockSums[t] : 0;
    lds[t] = v;
    __syncthreads();
    for (int off = 1; off < 256; off <<= 1) {
        int u = (t >= off) ? lds[t - off] : 0;
        __syncthreads();
        lds[t] += u;
        __syncthreads();
    }
    const int bid = blockIdx.x;
    const int base = (bid > 0) ? lds[bid - 1] : 0;
    const int total = lds[nb - 1];
    int i0 = bid * 512 + 2 * t;
#pragma unroll
    for (int q = 0; q < 2; q++) {
        int i = i0 + q;
        if (i < len) out[i] += base;
        else if (i == len) out[len] = total;
    }
}

// ---------------- P3: bucket partition (LDS ranks, no global atomics) ------

__global__ __launch_bounds__(256) void bucket_scatter_kernel(
    const int* __restrict__ src, const int* __restrict__ dst,
    const int* __restrict__ offs, int* __restrict__ esrc,
    unsigned char* __restrict__ dsub8, int e, int G1) {
    __shared__ unsigned int hist[256];
    hist[threadIdx.x] = 0;
    __syncthreads();
    int base = blockIdx.x * 2048 + threadIdx.x * 8;
    int d[8], s[8];
    if (base + 8 <= e) {
        int4 d0 = *(const int4*)(dst + base);
        int4 d1 = *(const int4*)(dst + base + 4);
        int4 s0 = *(const int4*)(src + base);
        int4 s1 = *(const int4*)(src + base + 4);
        d[0] = d0.x; d[1] = d0.y; d[2] = d0.z; d[3] = d0.w;
        d[4] = d1.x; d[5] = d1.y; d[6] = d1.z; d[7] = d1.w;
        s[0] = s0.x; s[1] = s0.y; s[2] = s0.z; s[3] = s0.w;
        s[4] = s1.x; s[5] = s1.y; s[6] = s1.z; s[7] = s1.w;
    } else {
#pragma unroll
        for (int j = 0; j < 8; j++) {
            int ij = base + j;
            bool v = ij < e;
            d[j] = v ? dst[ij] : -1;
            s[j] = v ? src[ij] : 0;
        }
    }
    unsigned lr[8];
#pragma unroll
    for (int j = 0; j < 8; j++) {
        lr[j] = (d[j] >= 0) ? atomicAdd(&hist[d[j] >> 8], 1u) : 0u;
    }
#pragma unroll
    for (int j = 0; j < 8; j++) {
        if (d[j] >= 0) {
            int pos = offs[(d[j] >> 8) * G1 + blockIdx.x] + (int)lr[j];
            esrc[pos] = s[j];
            dsub8[pos] = (unsigned char)(d[j] & 255);
        }
    }
}

// -------- P4: per-bucket CSR finalize: count -> scan -> row_ptr -> col -----

__global__ __launch_bounds__(256) void bucket_csr_kernel(
    const int* __restrict__ offs, const unsigned char* __restrict__ dsub8,
    const int* __restrict__ esrc, int* __restrict__ row_ptr,
    int* __restrict__ col, int G1, int n) {
    __shared__ unsigned int cnt[256];
    __shared__ int rp[256];
    int t = threadIdx.x;
    int b = blockIdx.x;
    cnt[t] = 0;
    __syncthreads();
    int bs = offs[b * G1];
    int be = offs[(b + 1) * G1];
    for (int i = bs + t; i < be; i += 256) {
        atomicAdd(&cnt[dsub8[i]], 1u);
    }
    __syncthreads();
    int v = (int)cnt[t];
    rp[t] = v;
    __syncthreads();
    for (int off = 1; off < 256; off <<= 1) {
        int u = (t >= off) ? rp[t - off] : 0;
        __syncthreads();
        rp[t] += u;
        __syncthreads();
    }
    int excl = rp[t] - v;
    int node = b * 256 + t;
    if (node <= n) row_ptr[node] = bs + excl;  // node==n lands here too (E)
    __syncthreads();
    cnt[t] = (unsigned)excl;  // running cursors
    __syncthreads();
    for (int i = bs + t; i < be; i += 256) {
        int sub = dsub8[i];
        unsigned r = atomicAdd(&cnt[sub], 1u);
        col[bs + (int)r] = esrc[i];
    }
}

// fp8 h byte position for channel c: 2-head interleaved pairs, 1-head flat
template <int OUT, int HEADS>
__device__ __forceinline__ int hpos8(int c) {
    return (HEADS == 2) ? (2 * (c & 63) + (c >> 6)) : c;
}

// ---------------- MFMA transform (K=128): h(fp8)=xb(bf16)@W, as/ad ---------

template <int OUT, int HEADS>
__global__ __launch_bounds__(256) void transform_mfma_kernel(
    const unsigned short* __restrict__ xb, const unsigned short* __restrict__ Wf,
    const float* __restrict__ a_src, const float* __restrict__ a_dst,
    unsigned char* __restrict__ h, float* __restrict__ as_o, float* __restrict__ ad_o,
    int n) {
    constexpr int T = OUT / 16, S = 4;  // K = 128
    const int w = threadIdx.x >> 6, lane = threadIdx.x & 63;
    const int node0 = (blockIdx.x * 4 + w) * 16;
    if (node0 >= n) return;
    const int quad = lane >> 4, col = lane & 15;

    const int arow = node0 + col;
    const bool aok = arow < n;
    bf16x8 a[S];
    const unsigned short* xrow = xb + (size_t)arow * 128 + quad * 8;
#pragma unroll
    for (int s = 0; s < S; s++) {
        bf16x8 z = {0, 0, 0, 0, 0, 0, 0, 0};
        a[s] = aok ? *(const bf16x8*)(xrow + s * 32) : z;
    }

    f32x4 acc[T];
#pragma unroll
    for (int t = 0; t < T; t++) acc[t] = (f32x4){0.f, 0.f, 0.f, 0.f};

#pragma unroll
    for (int s = 0; s < S; s++) {
#pragma unroll
        for (int t = 0; t < T; t++) {
            bf16x8 b = *(const bf16x8*)(Wf + ((size_t)(t * S + s) * 64 + lane) * 8);
            acc[t] = __builtin_amdgcn_mfma_f32_16x16x32_bf16(a[s], b, acc[t], 0, 0, 0);
        }
    }

#pragma unroll
    for (int t = 0; t < T; t++) {
        int pos = hpos8<OUT, HEADS>(t * 16 + col);
#pragma unroll
        for (int r = 0; r < 4; r++) {
            int m = node0 + quad * 4 + r;
            if (m < n) h[(size_t)m * OUT + pos] = f2fp8(acc[t][r]);
        }
    }

#pragma unroll
    for (int r = 0; r < 4; r++) {
        float s0 = 0.f, s1 = 0.f, d0 = 0.f, d1 = 0.f;
#pragma unroll
        for (int t = 0; t < T; t++) {
            float av = a_src[t * 16 + col];
            float dv = a_dst[t * 16 + col];
            float v = acc[t][r];
            if (HEADS == 2 && t >= T / 2) { s1 += v * av; d1 += v * dv; }
            else                          { s0 += v * av; d0 += v * dv; }
        }
        for (int off = 8; off; off >>= 1) {
            s0 += __shfl_xor(s0, off, 64);
            d0 += __shfl_xor(d0, off, 64);
            if (HEADS == 2) {
                s1 += __shfl_xor(s1, off, 64);
                d1 += __shfl_xor(d1, off, 64);
            }
        }
        int m = node0 + quad * 4 + r;
        if (m < n) {
            if (HEADS == 2) {
                if (col == 0)      { as_o[m * 2] = s0;     ad_o[m * 2] = d0; }
                else if (col == 1) { as_o[m * 2 + 1] = s1; ad_o[m * 2 + 1] = d1; }
            } else {
                if (col == 0) { as_o[m] = s0; ad_o[m] = d0; }
            }
        }
    }
}

// ------- GAT aggregation, 2 heads (fp8 h): TWO nodes per wave --------------
// Half-wave (32 lanes) per node; lane l gathers dword = ch {2l,2l+1} x 2
// heads. 32-edge chunks: weights at full lane util -> wave-private LDS ->
// uniform-per-half broadcast reads in 8-wide superrounds (8 loads in flight).

template <int ACT>  // 1 = elu
__global__ __launch_bounds__(256) void agg2_kernel(
    const int* __restrict__ row_ptr, const int* __restrict__ col,
    const unsigned char* __restrict__ h, const float2* __restrict__ as2,
    const float2* __restrict__ ad2, const float* __restrict__ bias,
    unsigned short* __restrict__ out, int n) {
    __shared__ float w0l[4][2][32], w1l[4][2][32];
    __shared__ unsigned sofl[4][2][32];
    const int w = threadIdx.x >> 6;
    const int lane = threadIdx.x & 63;
    const int half = lane >> 5, l = lane & 31;
    const int node = blockIdx.x * 8 + w * 2 + half;
    const bool active = node < n;

    int beg = 0, deg = 0;
    float2 adv = make_float2(0.f, 0.f);
    float den0 = 0.f, den1 = 0.f;
    float a0 = 0.f, a1 = 0.f, a2 = 0.f, a3 = 0.f;
    if (active) {
        beg = row_ptr[node];
        deg = row_ptr[node + 1] - beg;
        adv = ad2[node];
        float2 avs = as2[node];
        float w0s = __expf(LRELU(avs.x + adv.x));
        float w1s = __expf(LRELU(avs.y + adv.y));
        unsigned us = *(const unsigned*)(h + ((size_t)node << 7) + 4 * l);
        f32x2 p0 = fp8pair(us & 0xffffu);
        f32x2 p1 = fp8pair(us >> 16);
        a0 = w0s * p0.x; a1 = w1s * p0.y;
        a2 = w0s * p1.x; a3 = w1s * p1.y;
        den0 = w0s; den1 = w1s;
    }
    // wave-max degree (uniform outer loop)
    int dmax = deg;
    for (int off = 32; off; off >>= 1) dmax = max(dmax, __shfl_xor(dmax, off, 64));

    for (int base = 0; base < dmax; base += 32) {
        int cnt = deg - base;
        cnt = cnt < 0 ? 0 : (cnt > 32 ? 32 : cnt);
        float w0 = 0.f, w1 = 0.f;
        unsigned so = 0;
        if (l < cnt) {
            int s = col[beg + base + l];
            float2 av = as2[s];
            w0 = __expf(LRELU(av.x + adv.x));
            w1 = __expf(LRELU(av.y + adv.y));
            so = (unsigned)s << 7;
        }
        // half-local den reduce (xor 16..1 stays within the 32-lane half)
        float t0 = w0, t1 = w1;
        for (int off = 16; off; off >>= 1) {
            t0 += __shfl_xor(t0, off, 64);
            t1 += __shfl_xor(t1, off, 64);
        }
        den0 += t0; den1 += t1;
        w0l[w][half][l] = w0;
        w1l[w][half][l] = w1;
        sofl[w][half][l] = so;  // same-wave LDS RAW: compiler emits lgkmcnt

        int jmax = dmax - base;
        jmax = jmax > 32 ? 32 : jmax;
        for (int j = 0; j < jmax; j += 8) {
            unsigned u[8];
#pragma unroll
            for (int k = 0; k < 8; k++) {
                unsigned so_k = sofl[w][half][j + k];  // uniform per half
                u[k] = *(const unsigned*)(h + so_k + 4 * l);
            }
            float W0[8], W1[8];
#pragma unroll
            for (int k = 0; k < 8; k++) {
                W0[k] = w0l[w][half][j + k];
                W1[k] = w1l[w][half][j + k];
            }
#pragma unroll
            for (int k = 0; k < 8; k++) {
                f32x2 p0 = fp8pair(u[k] & 0xffffu);
                f32x2 p1 = fp8pair(u[k] >> 16);
                a0 += W0[k] * p0.x; a1 += W1[k] * p0.y;
                a2 += W0[k] * p1.x; a3 += W1[k] * p1.y;
            }
        }
    }

    if (active) {
        float2 bA = *(const float2*)(bias + 2 * l);       // head0 ch pair
        float2 bB = *(const float2*)(bias + 64 + 2 * l);  // head1 ch pair
        float r0 = 1.f / (den0 + 1e-16f), r1 = 1.f / (den1 + 1e-16f);
        float o0 = a0 * r0 + bA.x;  // ch2l   h0
        float o1 = a1 * r1 + bB.x;  // ch2l   h1
        float o2 = a2 * r0 + bA.y;  // ch2l+1 h0
        float o3 = a3 * r1 + bB.y;  // ch2l+1 h1
        if (ACT) {
            o0 = o0 > 0.f ? o0 : expm1f(o0);
            o1 = o1 > 0.f ? o1 : expm1f(o1);
            o2 = o2 > 0.f ? o2 : expm1f(o2);
            o3 = o3 > 0.f ? o3 : expm1f(o3);
        }
        unsigned h0 = (unsigned)f2bf(o0) | ((unsigned)f2bf(o2) << 16);
        unsigned h1 = (unsigned)f2bf(o1) | ((unsigned)f2bf(o3) << 16);
        *(unsigned*)(out + (size_t)node * 128 + 2 * l) = h0;
        *(unsigned*)(out + (size_t)node * 128 + 64 + 2 * l) = h1;
    }
}

// ------- GAT aggregation, 1 head (fp8 h, layer 2): two nodes per wave ------
// lane l gathers ushort = ch {2l,2l+1} of the 64B row. Output bf16.

__global__ __launch_bounds__(256) void agg1_kernel(
    const int* __restrict__ row_ptr, const int* __restrict__ col,
    const unsigned char* __restrict__ h, const float* __restrict__ as1,
    const float* __restrict__ ad1, const float* __restrict__ bias,
    unsigned short* __restrict__ out, int n) {
    __shared__ float wl[4][2][32];
    __shared__ unsigned sofl[4][2][32];
    const int w = threadIdx.x >> 6;
    const int lane = threadIdx.x & 63;
    const int half = lane >> 5, l = lane & 31;
    const int node = blockIdx.x * 8 + w * 2 + half;
    const bool active = node < n;

    int beg = 0, deg = 0;
    float adv = 0.f, den = 0.f, a0 = 0.f, a2 = 0.f;
    if (active) {
        beg = row_ptr[node];
        deg = row_ptr[node + 1] - beg;
        adv = ad1[node];
        float ws = __expf(LRELU(as1[node] + adv));
        unsigned us = *(const unsigned short*)(h + ((size_t)node << 6) + 2 * l);
        f32x2 p = fp8pair(us);
        a0 = ws * p.x;
        a2 = ws * p.y;
        den = ws;
    }
    int dmax = deg;
    for (int off = 32; off; off >>= 1) dmax = max(dmax, __shfl_xor(dmax, off, 64));

    for (int base = 0; base < dmax; base += 32) {
        int cnt = deg - base;
        cnt = cnt < 0 ? 0 : (cnt > 32 ? 32 : cnt);
        float w0 = 0.f;
        unsigned so = 0;
        if (l < cnt) {
            int s = col[beg + base + l];
            w0 = __expf(LRELU(as1[s] + adv));
            so = (unsigned)s << 6;
        }
        float t = w0;
        for (int off = 16; off; off >>= 1) t += __shfl_xor(t, off, 64);
        den += t;
        wl[w][half][l] = w0;
        sofl[w][half][l] = so;

        int jmax = dmax - base;
        jmax = jmax > 32 ? 32 : jmax;
        for (int j = 0; j < jmax; j += 8) {
            unsigned u[8];
#pragma unroll
            for (int k = 0; k < 8; k++) {
                unsigned so_k = sofl[w][half][j + k];
                u[k] = *(const unsigned short*)(h + so_k + 2 * l);
            }
            float W0[8];
#pragma unroll
            for (int k = 0; k < 8; k++) W0[k] = wl[w][half][j + k];
#pragma unroll
            for (int k = 0; k < 8; k++) {
                f32x2 p = fp8pair(u[k]);
                a0 += W0[k] * p.x;
                a2 += W0[k] * p.y;
            }
        }
    }

    if (active) {
        float2 bA = *(const float2*)(bias + 2 * l);
        float r = 1.f / (den + 1e-16f);
        float o0 = a0 * r + bA.x;
        float o2 = a2 * r + bA.y;
        unsigned hv = (unsigned)f2bf(o0) | ((unsigned)f2bf(o2) << 16);
        *(unsigned*)(out + (size_t)node * 64 + 2 * l) = hv;
    }
}

// ------- MLP head (pool fused): 512 threads/block, one block per graph -----

__global__ __launch_bounds__(512) void mlp_kernel(
    const unsigned short* __restrict__ xbuf, const int* __restrict__ gstart,
    const float* __restrict__ obs,
    const float* __restrict__ Ws1, const float* __restrict__ bs1,
    const float* __restrict__ ln_g, const float* __restrict__ ln_b,
    const float* __restrict__ Ws2, const float* __restrict__ bs2,
    const float* __restrict__ Wa, const float* __restrict__ ba,
    const float* __restrict__ Wc, const float* __restrict__ bc,
    float* __restrict__ out_logits, float* __restrict__ out_value) {
    int b = blockIdx.x;
    int t = threadIdx.x;
    __shared__ float comb[192];
    __shared__ float red[512];
    __shared__ float red2[8][64];
    __shared__ float hs[256];

    const int gs = gstart[b];
    const int ge = gstart[b + 1];

    // ---- pool: 64 rowgroups (8/wave) x 8 chunks of ushort8 ----
    {
        const int w = t >> 6, lane = t & 63;
        const int rg = w * 8 + (lane >> 3);   // global row-group 0..63
        const int sub = lane & 7;             // 8 ushort chunk
        float acc[8];
#pragma unroll
        for (int j = 0; j < 8; j++) acc[j] = 0.f;
        for (int i = gs + rg; i < ge; i += 64) {
            u16x8 v = *(const u16x8*)(xbuf + (size_t)i * 64 + sub * 8);
#pragma unroll
            for (int j = 0; j < 8; j++) acc[j] += bf2f(v[j]);
        }
#pragma unroll
        for (int off = 8; off <= 32; off <<= 1) {
#pragma unroll
            for (int j = 0; j < 8; j++) acc[j] += __shfl_xor(acc[j], off, 64);
        }
        if (lane < 8) {
#pragma unroll
            for (int j = 0; j < 8; j++) red2[w][lane * 8 + j] = acc[j];
        }
    }
    __syncthreads();
    {
        float cdiv = fmaxf((float)(ge - gs), 1.f);
        if (t < 64) {
            float s = 0.f;
#pragma unroll
            for (int w = 0; w < 8; w++) s += red2[w][t];
            comb[t] = s / cdiv;
        } else if (t < 192) {
            comb[t] = obs[b * 128 + (t - 64)];
        }
    }
    __syncthreads();

    const int t256 = t & 255;
    const int khalf = t >> 8;

    // ---- fc1: k split 2x96 ----
    {
        float accA = 0.f, accB = 0.f;
        int k0 = khalf * 96;
#pragma unroll 4
        for (int k = k0; k < k0 + 96; k += 2) {
            accA += comb[k] * Ws1[k * 256 + t256];
            accB += comb[k + 1] * Ws1[(k + 1) * 256 + t256];
        }
        red[t] = accA + accB;
    }
    __syncthreads();
    float acc = 0.f;
    if (t < 256) acc = bs1[t] + red[t] + red[t + 256];
    __syncthreads();

    // ---- LayerNorm over 256 ----
    red[t] = (t < 256) ? acc : 0.f;
    __syncthreads();
    for (int off = 128; off; off >>= 1) {
        if (t < off) red[t] += red[t + off];
        __syncthreads();
    }
    float mu = red[0] / 256.f;
    __syncthreads();
    float d = acc - mu;
    red[t] = (t < 256) ? d * d : 0.f;
    __syncthreads();
    for (int off = 128; off; off >>= 1) {
        if (t < off) red[t] += red[t + off];
        __syncthreads();
    }
    float var = red[0] / 256.f;
    if (t < 256) {
        float hn = d * rsqrtf(var + 1e-5f) * ln_g[t] + ln_b[t];
        hs[t] = hn > 0.f ? hn : 0.f;
    }
    __syncthreads();

    // ---- fc2: k split 2x128 ----
    {
        float a2A = 0.f, a2B = 0.f;
        int k0 = khalf * 128;
#pragma unroll 4
        for (int k = k0; k < k0 + 128; k += 2) {
            a2A += hs[k] * Ws2[k * 256 + t256];
            a2B += hs[k + 1] * Ws2[(k + 1) * 256 + t256];
        }
        red[t] = a2A + a2B;
    }
    __syncthreads();
    float acc2 = 0.f;
    if (t < 256) {
        acc2 = bs2[t] + red[t] + red[t + 256];
        acc2 = acc2 > 0.f ? acc2 : 0.f;
    }
    __syncthreads();
    if (t < 256) hs[t] = acc2;
    __syncthreads();

    // ---- logits: 16 outs x 32 k-chunks of 8 + LDS tree ----
    {
        int o = t & 15, ck = t >> 4;
        float p = 0.f;
#pragma unroll
        for (int k = 0; k < 8; k++)
            p += hs[ck * 8 + k] * Wa[(ck * 8 + k) * 16 + o];
        red[t] = p;
    }
    __syncthreads();
    for (int off = 16; off >= 1; off >>= 1) {
        if ((t >> 4) < off) red[t] += red[t + off * 16];
        __syncthreads();
    }
    if (t < 16) out_logits[b * 16 + t] = red[t] + ba[t];
    __syncthreads();

    // ---- value: full-width dot + tree over 512 ----
    red[t] = (t < 256) ? hs[t] * Wc[t] : 0.f;
    __syncthreads();
    for (int off = 256; off; off >>= 1) {
        if (t < off) red[t] += red[t + off];
        __syncthreads();
    }
    if (t == 0) out_value[b] = red[0] + bc[0];
}

// ---------------------------------------------------------------------------

extern "C" void kernel_launch(void* const* d_in, const int* in_sizes, int n_in,
                              void* d_out, int out_size, void* d_ws, size_t ws_size,
                              hipStream_t stream) {
    const float* obs    = (const float*)d_in[0];
    const float* nf     = (const float*)d_in[1];
    const int*   ei     = (const int*)d_in[2];
    const int*   batch  = (const int*)d_in[3];
    const float* W0     = (const float*)d_in[4];
    const float* a_src0 = (const float*)d_in[5];
    const float* a_dst0 = (const float*)d_in[6];
    const float* b0     = (const float*)d_in[7];
    const float* W1     = (const float*)d_in[8];
    const float* a_src1 = (const float*)d_in[9];
    const float* a_dst1 = (const float*)d_in[10];
    const float* b1     = (const float*)d_in[11];
    const float* W2     = (const float*)d_in[12];
    const float* a_src2 = (const float*)d_in[13];
    const float* a_dst2 = (const float*)d_in[14];
    const float* b2     = (const float*)d_in[15];
    const float* Ws1    = (const float*)d_in[16];
    const float* bs1    = (const float*)d_in[17];
    const float* ln_g   = (const float*)d_in[18];
    const float* ln_b   = (const float*)d_in[19];
    const float* Ws2    = (const float*)d_in[20];
    const float* bs2    = (const float*)d_in[21];
    const float* Wa     = (const float*)d_in[22];
    const float* ba     = (const float*)d_in[23];
    const float* Wc     = (const float*)d_in[24];
    const float* bc     = (const float*)d_in[25];

    const int N = in_sizes[3];
    const int E = in_sizes[2] / 2;
    const int B = in_sizes[0] / 128;
    const int* src = ei;
    const int* dstp = ei + E;

    // workspace carve (256B aligned)
    char* p = (char*)d_ws;
    auto alloc = [&](size_t bytes) -> void* {
        void* r = (void*)p;
        p += (bytes + 255) & ~(size_t)255;
        return r;
    };
    const int G1 = (E + 2047) / 2048;       // edge chunks (2048/block)
    const int NB = (N + 255) >> 8;          // dst buckets (n <= 65536)
    const int L  = NB * G1;                 // histT length
    int*   row_ptr   = (int*)alloc((size_t)(N + 1) * 4);
    int*   col       = (int*)alloc((size_t)E * 4);
    int*   esrc      = (int*)alloc((size_t)E * 4);           // bucketed src
    unsigned char* dsub8 = (unsigned char*)alloc((size_t)E); // bucketed dst&255
    int*   histT     = (int*)alloc((size_t)L * 4);
    int*   offs      = (int*)alloc((size_t)(L + 1) * 4);
    unsigned char* hbuf = (unsigned char*)alloc((size_t)N * 128);       // fp8 interleaved
    unsigned short* xb = (unsigned short*)alloc((size_t)N * 128 * 2);   // bf16 features
    unsigned short* xbuf = (unsigned short*)alloc((size_t)N * 64 * 2);  // final layer bf16
    float* as_       = (float*)alloc((size_t)N * 2 * 4);
    float* ad_       = (float*)alloc((size_t)N * 2 * 4);
    unsigned short* Wf1 = (unsigned short*)alloc((size_t)8 * 4 * 64 * 8 * 2);
    unsigned short* Wf2 = (unsigned short*)alloc((size_t)4 * 4 * 64 * 8 * 2);
    int* gstart      = (int*)alloc((size_t)(B + 1) * 4);
    // scratch (blockSums) aliases xb region: scanA completes (stream-ordered)
    // before xb's first write (agg2, layer 0).
    int* blockSums = (int*)xb;   // up to 256 entries

    float* out_logits = (float*)d_out;
    float* out_value  = out_logits + (size_t)B * 16;

    // ---- P1: hist || transform0 || W pack || gstart (1 dispatch) ----
    int t0_blocks = (N + 15) / 16;
    int wp_blocks = (8 * 4 * 64 + 4 * 4 * 64 + 255) / 256;
    int gb_blocks = (N + 255) / 256;
    hist_t0_kernel<<<G1 + t0_blocks + wp_blocks + gb_blocks, 256, 0, stream>>>(
        dstp, histT, E, G1, NB, N, G1, t0_blocks, wp_blocks,
        nf, W0, a_src0, a_dst0, hbuf, as_, ad_,
        W1, W2, Wf1, Wf2, batch, gstart, B);

    // ---- scanA over histT -> offs ----
    int nbA = (L + 511) / 512;
    scan2_block_kernel<<<nbA, 256, 0, stream>>>(histT, offs, blockSums, L);
    scan2_finalize_kernel<<<(L + 1 + 511) / 512, 256, 0, stream>>>(offs, blockSums, L, nbA);

    // ---- P3 bucket partition + P4 per-bucket CSR finalize ----
    bucket_scatter_kernel<<<G1, 256, 0, stream>>>(src, dstp, offs, esrc, dsub8, E, G1);
    bucket_csr_kernel<<<NB, 256, 0, stream>>>(offs, dsub8, esrc, row_ptr, col, G1, N);

    // ---- GAT layer 0 aggregation (transform fused into P1) ----
    agg2_kernel<1><<<(N + 7) / 8, 256, 0, stream>>>(
        row_ptr, col, hbuf, (const float2*)as_, (const float2*)ad_, b0, xb, N);

    // ---- GAT layer 1: in=128 -> concat, elu (MFMA transform) ----
    transform_mfma_kernel<128, 2><<<(N + 63) / 64, 256, 0, stream>>>(
        xb, Wf1, a_src1, a_dst1, hbuf, as_, ad_, N);
    agg2_kernel<1><<<(N + 7) / 8, 256, 0, stream>>>(
        row_ptr, col, hbuf, (const float2*)as_, (const float2*)ad_, b1, xb, N);

    // ---- GAT layer 2: in=128 -> heads=1, out=64 (MFMA transform) ----
    transform_mfma_kernel<64, 1><<<(N + 63) / 64, 256, 0, stream>>>(
        xb, Wf2, a_src2, a_dst2, hbuf, as_, ad_, N);
    agg1_kernel<<<(N + 7) / 8, 256, 0, stream>>>(
        row_ptr, col, hbuf, as_, ad_, b2, xbuf, N);

    // ---- MLP head with fused mean-pool (1 dispatch, no atomics) ----
    mlp_kernel<<<B, 512, 0, stream>>>(xbuf, gstart, obs, Ws1, bs1, ln_g, ln_b,
                                      Ws2, bs2, Wa, ba, Wc, bc,
                                      out_logits, out_value);
}